// Round 2
// baseline (647.512 us; speedup 1.0000x reference)
//
#include <hip/hip_runtime.h>
#include <hip/hip_bf16.h>

typedef __bf16 bf16;
typedef __bf16 bf16x8 __attribute__((ext_vector_type(8)));
typedef float f32x4 __attribute__((ext_vector_type(4)));

#define B_ 4
#define C_ 256
#define NH_ 4
#define KD_ 32
#define HD_ 64
#define N_ 4096
#define HQKV_ 512

// ---------------- weight convert ----------------
__global__ __launch_bounds__(256) void k_convw(const float* wq, const float* wp,
                                               bf16* wqb, bf16* wpb) {
    int i = blockIdx.x * 256 + threadIdx.x;
    if (i < HQKV_ * C_) wqb[i] = (bf16)wq[i];
    if (i < C_ * C_)    wpb[i] = (bf16)wp[i];
}

// ---------------- x (B,C,N) f32 -> xT (B,N,C) bf16 ----------------
__global__ __launch_bounds__(256) void k_transpose(const float* __restrict__ x,
                                                   bf16* __restrict__ xT) {
    __shared__ float tile[64][65];
    int b = blockIdx.z, c0 = blockIdx.y * 64, n0 = blockIdx.x * 64;
    int t = threadIdx.x;
    int lane = t & 63, wv = t >> 6;
    for (int k = 0; k < 16; ++k) {
        int cl = k * 4 + wv;
        tile[cl][lane] = x[((size_t)(b * C_ + c0 + cl)) * N_ + n0 + lane];
    }
    __syncthreads();
    for (int k = 0; k < 16; ++k) {
        int nl = k * 4 + wv;
        xT[((size_t)(b * N_ + n0 + nl)) * C_ + c0 + lane] = (bf16)tile[lane][nl];
    }
}

// ---------------- qkv GEMM: W(512x256) @ xT^T, writes q_t,k_t,(B,NH,N,32) v(B,NH,64,N) ----------------
__global__ __launch_bounds__(256) void k_qkv(const bf16* __restrict__ wqb,
                                             const bf16* __restrict__ xT,
                                             const float* __restrict__ bias,
                                             bf16* __restrict__ qt, bf16* __restrict__ kt,
                                             bf16* __restrict__ vb) {
    int n0 = blockIdx.x * 64, o0 = blockIdx.y * 64, b = blockIdx.z;
    int t = threadIdx.x, w = t >> 6, l = t & 63, lr = l & 15, lg = l >> 4;
    const bf16* arow = wqb + (size_t)(o0 + 16 * w + lr) * C_ + 8 * lg;
    const bf16* brow = xT + ((size_t)b * N_ + n0 + lr) * C_ + 8 * lg;
    f32x4 acc[4];
    f32x4 zz = {0.f, 0.f, 0.f, 0.f};
    acc[0] = zz; acc[1] = zz; acc[2] = zz; acc[3] = zz;
    for (int kk = 0; kk < C_; kk += 32) {
        bf16x8 a = *(const bf16x8*)(arow + kk);
#pragma unroll
        for (int tt = 0; tt < 4; ++tt) {
            bf16x8 bb = *(const bf16x8*)(brow + (size_t)tt * 16 * C_ + kk);
            acc[tt] = __builtin_amdgcn_mfma_f32_16x16x32_bf16(a, bb, acc[tt], 0, 0, 0);
        }
    }
    const float scale = 0.17677669529663687f;  // KD^-0.5 folded into q
#pragma unroll
    for (int tt = 0; tt < 4; ++tt) {
        int n = n0 + 16 * tt + lr;
#pragma unroll
        for (int j = 0; j < 4; ++j) {
            int o = o0 + 16 * w + 4 * lg + j;
            float val = acc[tt][j] + bias[o];
            int h = o >> 7, r = o & 127;
            size_t bh = (size_t)(b * NH_ + h);
            if (r < KD_)            qt[(bh * N_ + n) * KD_ + r] = (bf16)(val * scale);
            else if (r < 2 * KD_)   kt[(bh * N_ + n) * KD_ + (r - KD_)] = (bf16)val;
            else                    vb[(bh * HD_ + (r - 2 * KD_)) * N_ + n] = (bf16)val;
        }
    }
}

// ---------------- fused flash attention, writes attnT (B,N,C) f32 ----------------
__global__ __launch_bounds__(256) void k_attn(const bf16* __restrict__ qt,
                                              const bf16* __restrict__ kt,
                                              const bf16* __restrict__ vb,
                                              float* __restrict__ attnT) {
    __shared__ bf16 lds_p[4 * 16 * 72];
    int n0 = blockIdx.x * 64;
    int bh = blockIdx.y;  // b*NH + h
    int b = bh >> 2, h = bh & 3;
    int t = threadIdx.x, w = t >> 6, l = t & 63, lr = l & 15, lg = l >> 4;
    bf16x8 aq = *(const bf16x8*)(qt + ((size_t)bh * N_ + n0 + 16 * w + lr) * KD_ + 8 * lg);
    float M[4] = {-1e30f, -1e30f, -1e30f, -1e30f};
    float L[4] = {0.f, 0.f, 0.f, 0.f};
    f32x4 zz = {0.f, 0.f, 0.f, 0.f};
    f32x4 oacc[4];
    oacc[0] = zz; oacc[1] = zz; oacc[2] = zz; oacc[3] = zz;
    bf16* myp = lds_p + w * 16 * 72;

    for (int m0 = 0; m0 < N_; m0 += 64) {
        f32x4 s[4];
#pragma unroll
        for (int tt = 0; tt < 4; ++tt) {
            bf16x8 kb = *(const bf16x8*)(kt + ((size_t)bh * N_ + m0 + 16 * tt + lr) * KD_ + 8 * lg);
            s[tt] = __builtin_amdgcn_mfma_f32_16x16x32_bf16(aq, kb, zz, 0, 0, 0);
        }
        float p[4][4];
        float alpha[4];
#pragma unroll
        for (int j = 0; j < 4; ++j) {
            float mloc = fmaxf(fmaxf(s[0][j], s[1][j]), fmaxf(s[2][j], s[3][j]));
#pragma unroll
            for (int d = 1; d < 16; d <<= 1) mloc = fmaxf(mloc, __shfl_xor(mloc, d));
            float Mn = fmaxf(M[j], mloc);
            alpha[j] = __expf(M[j] - Mn);
            M[j] = Mn;
            float rs = 0.f;
#pragma unroll
            for (int tt = 0; tt < 4; ++tt) {
                float pv = __expf(s[tt][j] - Mn);
                p[tt][j] = pv;
                rs += pv;
            }
#pragma unroll
            for (int d = 1; d < 16; d <<= 1) rs += __shfl_xor(rs, d);
            L[j] = L[j] * alpha[j] + rs;
        }
#pragma unroll
        for (int tt = 0; tt < 4; ++tt)
#pragma unroll
            for (int j = 0; j < 4; ++j)
                myp[(4 * lg + j) * 72 + 16 * tt + lr] = (bf16)p[tt][j];
#pragma unroll
        for (int dt = 0; dt < 4; ++dt)
#pragma unroll
            for (int j = 0; j < 4; ++j) oacc[dt][j] *= alpha[j];
        __syncthreads();
#pragma unroll
        for (int ks = 0; ks < 2; ++ks) {
            bf16x8 pa = *(const bf16x8*)(myp + lr * 72 + 32 * ks + 8 * lg);
#pragma unroll
            for (int dt = 0; dt < 4; ++dt) {
                bf16x8 bv = *(const bf16x8*)(vb + ((size_t)bh * HD_ + 16 * dt + lr) * N_ + m0 + 32 * ks + 8 * lg);
                oacc[dt] = __builtin_amdgcn_mfma_f32_16x16x32_bf16(pa, bv, oacc[dt], 0, 0, 0);
            }
        }
        __syncthreads();
    }
#pragma unroll
    for (int dt = 0; dt < 4; ++dt)
#pragma unroll
        for (int j = 0; j < 4; ++j) {
            int n = n0 + 16 * w + 4 * lg + j;
            attnT[((size_t)b * N_ + n) * C_ + h * HD_ + 16 * dt + lr] = oacc[dt][j] / L[j];
        }
}

// ---------------- y = attn + dwconv3(v)+b_pe; writes yT (B,N,C) bf16 ----------------
__global__ __launch_bounds__(256) void k_pe_add(const float* __restrict__ attnT,
                                                const bf16* __restrict__ vb,
                                                const float* __restrict__ wpe,
                                                const float* __restrict__ bpe,
                                                bf16* __restrict__ yT) {
    __shared__ float tile[64 * 257];
    int hh = blockIdx.x, b = blockIdx.y;
    int t = threadIdx.x;
    for (int k = 0; k < 64; ++k)
        tile[k * 257 + t] = attnT[((size_t)b * N_ + hh * 64 + k) * C_ + t];
    __syncthreads();
    int ww = t & 63, cg = t >> 6;
    for (int ci = 0; ci < 64; ++ci) {
        int c = cg * 64 + ci;
        const bf16* vrow = vb + (size_t)(b * C_ + c) * N_;
        float acc = bpe[c];
#pragma unroll
        for (int kh = 0; kh < 3; ++kh) {
            int hh2 = hh + kh - 1;
            if (hh2 < 0 || hh2 >= 64) continue;
#pragma unroll
            for (int kw = 0; kw < 3; ++kw) {
                int ww2 = ww + kw - 1;
                if (ww2 < 0 || ww2 >= 64) continue;
                acc += (float)vrow[hh2 * 64 + ww2] * wpe[c * 9 + kh * 3 + kw];
            }
        }
        tile[ww * 257 + c] += acc;
    }
    __syncthreads();
    for (int k = 0; k < 64; ++k)
        yT[((size_t)b * N_ + hh * 64 + k) * C_ + t] = (bf16)tile[k * 257 + t];
}

// ---------------- proj GEMM + residual: x2 = x + Wp @ y + b ----------------
__global__ __launch_bounds__(256) void k_proj(const bf16* __restrict__ wpb,
                                              const bf16* __restrict__ yT,
                                              const float* __restrict__ bias,
                                              const float* __restrict__ x,
                                              float* __restrict__ x2) {
    int n0 = blockIdx.x * 64, o0 = blockIdx.y * 64, b = blockIdx.z;
    int t = threadIdx.x, w = t >> 6, l = t & 63, lr = l & 15, lg = l >> 4;
    const bf16* arow = wpb + (size_t)(o0 + 16 * w + lr) * C_ + 8 * lg;
    const bf16* brow = yT + ((size_t)b * N_ + n0 + lr) * C_ + 8 * lg;
    f32x4 acc[4];
    f32x4 zz = {0.f, 0.f, 0.f, 0.f};
    acc[0] = zz; acc[1] = zz; acc[2] = zz; acc[3] = zz;
    for (int kk = 0; kk < C_; kk += 32) {
        bf16x8 a = *(const bf16x8*)(arow + kk);
#pragma unroll
        for (int tt = 0; tt < 4; ++tt) {
            bf16x8 bb = *(const bf16x8*)(brow + (size_t)tt * 16 * C_ + kk);
            acc[tt] = __builtin_amdgcn_mfma_f32_16x16x32_bf16(a, bb, acc[tt], 0, 0, 0);
        }
    }
#pragma unroll
    for (int tt = 0; tt < 4; ++tt) {
        int n = n0 + 16 * tt + lr;
#pragma unroll
        for (int j = 0; j < 4; ++j) {
            int o = o0 + 16 * w + 4 * lg + j;
            size_t idx = ((size_t)b * C_ + o) * N_ + n;
            x2[idx] = x[idx] + acc[tt][j] + bias[o];
        }
    }
}

// ---------------- channel attention: reduce ----------------
__global__ __launch_bounds__(256) void k_ca_red(const float* __restrict__ x2,
                                                float* __restrict__ avg, float* __restrict__ mx) {
    int bc = blockIdx.x;
    int t = threadIdx.x;
    const float* row = x2 + (size_t)bc * N_;
    float s = 0.f, m = -1e30f;
    for (int i = t; i < N_; i += 256) { float v = row[i]; s += v; m = fmaxf(m, v); }
#pragma unroll
    for (int d = 1; d < 64; d <<= 1) { s += __shfl_xor(s, d); m = fmaxf(m, __shfl_xor(m, d)); }
    __shared__ float ss[4], sm[4];
    int w = t >> 6;
    if ((t & 63) == 0) { ss[w] = s; sm[w] = m; }
    __syncthreads();
    if (t == 0) {
        avg[bc] = (ss[0] + ss[1] + ss[2] + ss[3]) / (float)N_;
        mx[bc] = fmaxf(fmaxf(sm[0], sm[1]), fmaxf(sm[2], sm[3]));
    }
}

// ---------------- channel attention: MLP ----------------
__global__ __launch_bounds__(256) void k_ca_mlp(const float* __restrict__ avg,
                                                const float* __restrict__ mx,
                                                const float* __restrict__ wfc1,
                                                const float* __restrict__ wfc2,
                                                float* __restrict__ ca) {
    int b = blockIdx.x, t = threadIdx.x;
    __shared__ float hsum[16];
    if (t < 16) {
        const float* w1 = wfc1 + t * C_;
        float ha = 0.f, hm = 0.f;
        for (int c = 0; c < C_; ++c) { ha += avg[b * C_ + c] * w1[c]; hm += mx[b * C_ + c] * w1[c]; }
        hsum[t] = fmaxf(ha, 0.f) + fmaxf(hm, 0.f);
    }
    __syncthreads();
    float o = 0.f;
    const float* w2 = wfc2 + t * 16;
#pragma unroll
    for (int r = 0; r < 16; ++r) o += hsum[r] * w2[r];
    ca[b * C_ + t] = 1.f / (1.f + __expf(-o));
}

// ---------------- spatial attention: channel reduce of x2*ca ----------------
__global__ __launch_bounds__(256) void k_sa_red(const float* __restrict__ x2,
                                                const float* __restrict__ ca,
                                                float* __restrict__ sain) {
    int b = blockIdx.y;
    int n = blockIdx.x * 256 + threadIdx.x;
    __shared__ float cal[C_];
    cal[threadIdx.x] = ca[b * C_ + threadIdx.x];
    __syncthreads();
    float s = 0.f, m = -1e30f;
    for (int c = 0; c < C_; ++c) {
        float v = x2[((size_t)b * C_ + c) * N_ + n] * cal[c];
        s += v; m = fmaxf(m, v);
    }
    sain[((size_t)b * 2 + 0) * N_ + n] = s * (1.f / C_);
    sain[((size_t)b * 2 + 1) * N_ + n] = m;
}

// ---------------- final: sa conv + sigmoid + output (f32!) ----------------
__global__ __launch_bounds__(256) void k_final(const float* __restrict__ x2,
                                               const float* __restrict__ ca,
                                               const float* __restrict__ sain,
                                               const float* __restrict__ wsa,
                                               float* __restrict__ out) {
    int b = blockIdx.y;
    int n = blockIdx.x * 256 + threadIdx.x;
    __shared__ float cal[C_];
    cal[threadIdx.x] = ca[b * C_ + threadIdx.x];
    __syncthreads();
    int hh = n >> 6, ww = n & 63;
    float acc = 0.f;
#pragma unroll
    for (int i = 0; i < 2; ++i)
#pragma unroll
        for (int kh = 0; kh < 3; ++kh) {
            int hh2 = hh + kh - 1;
            if (hh2 < 0 || hh2 >= 64) continue;
#pragma unroll
            for (int kw = 0; kw < 3; ++kw) {
                int ww2 = ww + kw - 1;
                if (ww2 < 0 || ww2 >= 64) continue;
                acc += sain[((size_t)b * 2 + i) * N_ + hh2 * 64 + ww2] * wsa[i * 9 + kh * 3 + kw];
            }
        }
    float sa = 1.f / (1.f + __expf(-acc));
    for (int c = 0; c < C_; ++c) {
        size_t idx = ((size_t)b * C_ + c) * N_ + n;
        out[idx] = x2[idx] * cal[c] * sa;
    }
}

extern "C" void kernel_launch(void* const* d_in, const int* in_sizes, int n_in,
                              void* d_out, int out_size, void* d_ws, size_t ws_size,
                              hipStream_t stream) {
    const float* x     = (const float*)d_in[0];
    const float* wqkv  = (const float*)d_in[1];
    const float* bqkv  = (const float*)d_in[2];
    const float* wproj = (const float*)d_in[3];
    const float* bproj = (const float*)d_in[4];
    const float* wpe   = (const float*)d_in[5];
    const float* bpe   = (const float*)d_in[6];
    const float* wfc1  = (const float*)d_in[7];
    const float* wfc2  = (const float*)d_in[8];
    const float* wsa   = (const float*)d_in[9];
    float* out = (float*)d_out;  // reference output dtype is float32

    char* ws = (char*)d_ws;
    size_t off = 0;
    auto alloc = [&](size_t bytes) {
        char* p = ws + off;
        off += (bytes + 255) & ~(size_t)255;
        return p;
    };
    bf16*  qt    = (bf16*)alloc((size_t)B_ * NH_ * N_ * KD_ * 2);
    bf16*  ktb   = (bf16*)alloc((size_t)B_ * NH_ * N_ * KD_ * 2);
    bf16*  vbuf  = (bf16*)alloc((size_t)B_ * NH_ * HD_ * N_ * 2);
    bf16*  xT    = (bf16*)alloc((size_t)B_ * N_ * C_ * 2);
    float* attnT = (float*)alloc((size_t)B_ * N_ * C_ * 4);
    float* x2    = (float*)alloc((size_t)B_ * C_ * N_ * 4);
    bf16*  wqb   = (bf16*)alloc((size_t)HQKV_ * C_ * 2);
    bf16*  wpb   = (bf16*)alloc((size_t)C_ * C_ * 2);
    float* avg   = (float*)alloc(B_ * C_ * 4);
    float* mxb   = (float*)alloc(B_ * C_ * 4);
    float* cab   = (float*)alloc(B_ * C_ * 4);
    float* sain  = (float*)alloc((size_t)B_ * 2 * N_ * 4);
    bf16*  yT    = xT;  // alias: xT dead after k_qkv completes (stream-ordered)

    k_convw<<<dim3((HQKV_ * C_ + 255) / 256), 256, 0, stream>>>(wqkv, wproj, wqb, wpb);
    k_transpose<<<dim3(64, 4, B_), 256, 0, stream>>>(x, xT);
    k_qkv<<<dim3(64, 8, B_), 256, 0, stream>>>(wqb, xT, bqkv, qt, ktb, vbuf);
    k_attn<<<dim3(64, B_ * NH_), 256, 0, stream>>>(qt, ktb, vbuf, attnT);
    k_pe_add<<<dim3(64, B_), 256, 0, stream>>>(attnT, vbuf, wpe, bpe, yT);
    k_proj<<<dim3(64, 4, B_), 256, 0, stream>>>(wpb, yT, bproj, x, x2);
    k_ca_red<<<dim3(B_ * C_), 256, 0, stream>>>(x2, avg, mxb);
    k_ca_mlp<<<dim3(B_), 256, 0, stream>>>(avg, mxb, wfc1, wfc2, cab);
    k_sa_red<<<dim3(16, B_), 256, 0, stream>>>(x2, cab, sain);
    k_final<<<dim3(16, B_), 256, 0, stream>>>(x2, cab, sain, wsa, out);
}

// Round 3
// 498.486 us; speedup vs baseline: 1.2990x; 1.2990x over previous
//
#include <hip/hip_runtime.h>
#include <hip/hip_bf16.h>

typedef __bf16 bf16;
typedef __bf16 bf16x4 __attribute__((ext_vector_type(4)));
typedef __bf16 bf16x8 __attribute__((ext_vector_type(8)));
typedef float f32x4 __attribute__((ext_vector_type(4)));

#define B_ 4
#define C_ 256
#define NH_ 4
#define KD_ 32
#define HD_ 64
#define N_ 4096
#define HQKV_ 512

// ---------------- weight convert ----------------
__global__ __launch_bounds__(256) void k_convw(const float* wq, const float* wp,
                                               bf16* wqb, bf16* wpb) {
    int i = blockIdx.x * 256 + threadIdx.x;
    if (i < HQKV_ * C_) wqb[i] = (bf16)wq[i];
    if (i < C_ * C_)    wpb[i] = (bf16)wp[i];
}

// ---------------- x (B,C,N) f32 -> xT (B,N,C) bf16 ----------------
__global__ __launch_bounds__(256) void k_transpose(const float* __restrict__ x,
                                                   bf16* __restrict__ xT) {
    __shared__ float tile[64][65];
    int b = blockIdx.z, c0 = blockIdx.y * 64, n0 = blockIdx.x * 64;
    int t = threadIdx.x;
    int lane = t & 63, wv = t >> 6;
    for (int k = 0; k < 16; ++k) {
        int cl = k * 4 + wv;
        tile[cl][lane] = x[((size_t)(b * C_ + c0 + cl)) * N_ + n0 + lane];
    }
    __syncthreads();
    for (int k = 0; k < 16; ++k) {
        int nl = k * 4 + wv;
        xT[((size_t)(b * N_ + n0 + nl)) * C_ + c0 + lane] = (bf16)tile[lane][nl];
    }
}

// ---------------- qkv GEMM: W(512x256) @ xT^T, writes q_t,k_t,(B,NH,N,32) v(B,NH,64,N) ----------------
__global__ __launch_bounds__(256) void k_qkv(const bf16* __restrict__ wqb,
                                             const bf16* __restrict__ xT,
                                             const float* __restrict__ bias,
                                             bf16* __restrict__ qt, bf16* __restrict__ kt,
                                             bf16* __restrict__ vb) {
    int n0 = blockIdx.x * 64, o0 = blockIdx.y * 64, b = blockIdx.z;
    int t = threadIdx.x, w = t >> 6, l = t & 63, lr = l & 15, lg = l >> 4;
    const bf16* arow = wqb + (size_t)(o0 + 16 * w + lr) * C_ + 8 * lg;
    const bf16* brow = xT + ((size_t)b * N_ + n0 + lr) * C_ + 8 * lg;
    f32x4 acc[4];
    f32x4 zz = {0.f, 0.f, 0.f, 0.f};
    acc[0] = zz; acc[1] = zz; acc[2] = zz; acc[3] = zz;
    for (int kk = 0; kk < C_; kk += 32) {
        bf16x8 a = *(const bf16x8*)(arow + kk);
#pragma unroll
        for (int tt = 0; tt < 4; ++tt) {
            bf16x8 bb = *(const bf16x8*)(brow + (size_t)tt * 16 * C_ + kk);
            acc[tt] = __builtin_amdgcn_mfma_f32_16x16x32_bf16(a, bb, acc[tt], 0, 0, 0);
        }
    }
    // KD^-0.5 * log2(e) folded into q so attention can use raw exp2
    const float scale = 0.25506953076085663f;
#pragma unroll
    for (int tt = 0; tt < 4; ++tt) {
        int n = n0 + 16 * tt + lr;
#pragma unroll
        for (int j = 0; j < 4; ++j) {
            int o = o0 + 16 * w + 4 * lg + j;
            float val = acc[tt][j] + bias[o];
            int h = o >> 7, r = o & 127;
            size_t bh = (size_t)(b * NH_ + h);
            if (r < KD_)            qt[(bh * N_ + n) * KD_ + r] = (bf16)(val * scale);
            else if (r < 2 * KD_)   kt[(bh * N_ + n) * KD_ + (r - KD_)] = (bf16)val;
            else                    vb[(bh * HD_ + (r - 2 * KD_)) * N_ + n] = (bf16)val;
        }
    }
}

// ---------------- fused flash attention (no-max softmax, barrier-free) ----------------
// Swapped QK^T: S = mfma(K, Q) so D holds P[m=4*lg+j+16*tt][n=lr].
// P written m-contiguous (ds_write_b64), read back as A-fragment (b128).
// LDS tile is strictly per-wave -> no __syncthreads anywhere.
__global__ __launch_bounds__(256) void k_attn(const bf16* __restrict__ qt,
                                              const bf16* __restrict__ kt,
                                              const bf16* __restrict__ vb,
                                              float* __restrict__ attnT) {
    __shared__ bf16 lds_p[4 * 16 * 72];
    int n0 = blockIdx.x * 64;
    int bh = blockIdx.y;  // b*NH + h
    int b = bh >> 2, h = bh & 3;
    int t = threadIdx.x, w = t >> 6, l = t & 63, lr = l & 15, lg = l >> 4;
    bf16x8 aq = *(const bf16x8*)(qt + ((size_t)bh * N_ + n0 + 16 * w + lr) * KD_ + 8 * lg);
    f32x4 zz = {0.f, 0.f, 0.f, 0.f};
    f32x4 Lacc = zz;  // 4 independent partial-sum chains (all for row n=lr)
    f32x4 oacc[4];
    oacc[0] = zz; oacc[1] = zz; oacc[2] = zz; oacc[3] = zz;
    bf16* myp = lds_p + w * 16 * 72;

    const bf16* kbase = kt + ((size_t)bh * N_ + lr) * KD_ + 8 * lg;
    const bf16* vbase = vb + ((size_t)bh * HD_ + lr) * N_ + 8 * lg;

    for (int m0 = 0; m0 < N_; m0 += 64) {
        f32x4 s[4];
#pragma unroll
        for (int tt = 0; tt < 4; ++tt) {
            bf16x8 kb = *(const bf16x8*)(kbase + (size_t)(m0 + 16 * tt) * KD_);
            s[tt] = __builtin_amdgcn_mfma_f32_16x16x32_bf16(kb, aq, zz, 0, 0, 0);
        }
#pragma unroll
        for (int tt = 0; tt < 4; ++tt) {
            bf16x4 pk;
#pragma unroll
            for (int j = 0; j < 4; ++j) {
                float pv = __builtin_amdgcn_exp2f(s[tt][j]);
                Lacc[j] += pv;
                pk[j] = (bf16)pv;
            }
            *(bf16x4*)(myp + lr * 72 + 16 * tt + 4 * lg) = pk;
        }
#pragma unroll
        for (int ks = 0; ks < 2; ++ks) {
            bf16x8 pa = *(const bf16x8*)(myp + lr * 72 + 32 * ks + 8 * lg);
#pragma unroll
            for (int dt = 0; dt < 4; ++dt) {
                bf16x8 bv = *(const bf16x8*)(vbase + (size_t)(16 * dt) * N_ + m0 + 32 * ks);
                oacc[dt] = __builtin_amdgcn_mfma_f32_16x16x32_bf16(pa, bv, oacc[dt], 0, 0, 0);
            }
        }
    }
    // row-sum L for n=lr: reduce the 4 chains, then across lg groups
    float Lp = Lacc[0] + Lacc[1] + Lacc[2] + Lacc[3];
    Lp += __shfl_xor(Lp, 16);
    Lp += __shfl_xor(Lp, 32);
    float inv[4];
#pragma unroll
    for (int j = 0; j < 4; ++j) inv[j] = 1.f / __shfl(Lp, 4 * lg + j);
#pragma unroll
    for (int dt = 0; dt < 4; ++dt)
#pragma unroll
        for (int j = 0; j < 4; ++j) {
            int n = n0 + 16 * w + 4 * lg + j;
            attnT[((size_t)b * N_ + n) * C_ + h * HD_ + 16 * dt + lr] = oacc[dt][j] * inv[j];
        }
}

// ---------------- y = attn + dwconv3(v)+b_pe; writes yT (B,N,C) bf16 ----------------
__global__ __launch_bounds__(256) void k_pe_add(const float* __restrict__ attnT,
                                                const bf16* __restrict__ vb,
                                                const float* __restrict__ wpe,
                                                const float* __restrict__ bpe,
                                                bf16* __restrict__ yT) {
    __shared__ float tile[64 * 257];
    int hh = blockIdx.x, b = blockIdx.y;
    int t = threadIdx.x;
    for (int k = 0; k < 64; ++k)
        tile[k * 257 + t] = attnT[((size_t)b * N_ + hh * 64 + k) * C_ + t];
    __syncthreads();
    int ww = t & 63, cg = t >> 6;
    for (int ci = 0; ci < 64; ++ci) {
        int c = cg * 64 + ci;
        const bf16* vrow = vb + (size_t)(b * C_ + c) * N_;
        float acc = bpe[c];
#pragma unroll
        for (int kh = 0; kh < 3; ++kh) {
            int hh2 = hh + kh - 1;
            if (hh2 < 0 || hh2 >= 64) continue;
#pragma unroll
            for (int kw = 0; kw < 3; ++kw) {
                int ww2 = ww + kw - 1;
                if (ww2 < 0 || ww2 >= 64) continue;
                acc += (float)vrow[hh2 * 64 + ww2] * wpe[c * 9 + kh * 3 + kw];
            }
        }
        tile[ww * 257 + c] += acc;
    }
    __syncthreads();
    for (int k = 0; k < 64; ++k)
        yT[((size_t)b * N_ + hh * 64 + k) * C_ + t] = (bf16)tile[k * 257 + t];
}

// ---------------- proj GEMM + residual: x2 = x + Wp @ y + b ----------------
__global__ __launch_bounds__(256) void k_proj(const bf16* __restrict__ wpb,
                                              const bf16* __restrict__ yT,
                                              const float* __restrict__ bias,
                                              const float* __restrict__ x,
                                              float* __restrict__ x2) {
    int n0 = blockIdx.x * 64, o0 = blockIdx.y * 64, b = blockIdx.z;
    int t = threadIdx.x, w = t >> 6, l = t & 63, lr = l & 15, lg = l >> 4;
    const bf16* arow = wpb + (size_t)(o0 + 16 * w + lr) * C_ + 8 * lg;
    const bf16* brow = yT + ((size_t)b * N_ + n0 + lr) * C_ + 8 * lg;
    f32x4 acc[4];
    f32x4 zz = {0.f, 0.f, 0.f, 0.f};
    acc[0] = zz; acc[1] = zz; acc[2] = zz; acc[3] = zz;
    for (int kk = 0; kk < C_; kk += 32) {
        bf16x8 a = *(const bf16x8*)(arow + kk);
#pragma unroll
        for (int tt = 0; tt < 4; ++tt) {
            bf16x8 bb = *(const bf16x8*)(brow + (size_t)tt * 16 * C_ + kk);
            acc[tt] = __builtin_amdgcn_mfma_f32_16x16x32_bf16(a, bb, acc[tt], 0, 0, 0);
        }
    }
#pragma unroll
    for (int tt = 0; tt < 4; ++tt) {
        int n = n0 + 16 * tt + lr;
#pragma unroll
        for (int j = 0; j < 4; ++j) {
            int o = o0 + 16 * w + 4 * lg + j;
            size_t idx = ((size_t)b * C_ + o) * N_ + n;
            x2[idx] = x[idx] + acc[tt][j] + bias[o];
        }
    }
}

// ---------------- channel attention: reduce ----------------
__global__ __launch_bounds__(256) void k_ca_red(const float* __restrict__ x2,
                                                float* __restrict__ avg, float* __restrict__ mx) {
    int bc = blockIdx.x;
    int t = threadIdx.x;
    const float* row = x2 + (size_t)bc * N_;
    float s = 0.f, m = -1e30f;
    for (int i = t; i < N_; i += 256) { float v = row[i]; s += v; m = fmaxf(m, v); }
#pragma unroll
    for (int d = 1; d < 64; d <<= 1) { s += __shfl_xor(s, d); m = fmaxf(m, __shfl_xor(m, d)); }
    __shared__ float ss[4], sm[4];
    int w = t >> 6;
    if ((t & 63) == 0) { ss[w] = s; sm[w] = m; }
    __syncthreads();
    if (t == 0) {
        avg[bc] = (ss[0] + ss[1] + ss[2] + ss[3]) / (float)N_;
        mx[bc] = fmaxf(fmaxf(sm[0], sm[1]), fmaxf(sm[2], sm[3]));
    }
}

// ---------------- channel attention: MLP ----------------
__global__ __launch_bounds__(256) void k_ca_mlp(const float* __restrict__ avg,
                                                const float* __restrict__ mx,
                                                const float* __restrict__ wfc1,
                                                const float* __restrict__ wfc2,
                                                float* __restrict__ ca) {
    int b = blockIdx.x, t = threadIdx.x;
    __shared__ float hsum[16];
    if (t < 16) {
        const float* w1 = wfc1 + t * C_;
        float ha = 0.f, hm = 0.f;
        for (int c = 0; c < C_; ++c) { ha += avg[b * C_ + c] * w1[c]; hm += mx[b * C_ + c] * w1[c]; }
        hsum[t] = fmaxf(ha, 0.f) + fmaxf(hm, 0.f);
    }
    __syncthreads();
    float o = 0.f;
    const float* w2 = wfc2 + t * 16;
#pragma unroll
    for (int r = 0; r < 16; ++r) o += hsum[r] * w2[r];
    ca[b * C_ + t] = 1.f / (1.f + __expf(-o));
}

// ---------------- spatial attention: channel reduce of x2*ca ----------------
__global__ __launch_bounds__(256) void k_sa_red(const float* __restrict__ x2,
                                                const float* __restrict__ ca,
                                                float* __restrict__ sain) {
    int b = blockIdx.y;
    int n = blockIdx.x * 256 + threadIdx.x;
    __shared__ float cal[C_];
    cal[threadIdx.x] = ca[b * C_ + threadIdx.x];
    __syncthreads();
    float s = 0.f, m = -1e30f;
    for (int c = 0; c < C_; ++c) {
        float v = x2[((size_t)b * C_ + c) * N_ + n] * cal[c];
        s += v; m = fmaxf(m, v);
    }
    sain[((size_t)b * 2 + 0) * N_ + n] = s * (1.f / C_);
    sain[((size_t)b * 2 + 1) * N_ + n] = m;
}

// ---------------- final: sa conv + sigmoid + output (f32) ----------------
__global__ __launch_bounds__(256) void k_final(const float* __restrict__ x2,
                                               const float* __restrict__ ca,
                                               const float* __restrict__ sain,
                                               const float* __restrict__ wsa,
                                               float* __restrict__ out) {
    int b = blockIdx.y;
    int n = blockIdx.x * 256 + threadIdx.x;
    __shared__ float cal[C_];
    cal[threadIdx.x] = ca[b * C_ + threadIdx.x];
    __syncthreads();
    int hh = n >> 6, ww = n & 63;
    float acc = 0.f;
#pragma unroll
    for (int i = 0; i < 2; ++i)
#pragma unroll
        for (int kh = 0; kh < 3; ++kh) {
            int hh2 = hh + kh - 1;
            if (hh2 < 0 || hh2 >= 64) continue;
#pragma unroll
            for (int kw = 0; kw < 3; ++kw) {
                int ww2 = ww + kw - 1;
                if (ww2 < 0 || ww2 >= 64) continue;
                acc += sain[((size_t)b * 2 + i) * N_ + hh2 * 64 + ww2] * wsa[i * 9 + kh * 3 + kw];
            }
        }
    float sa = 1.f / (1.f + __expf(-acc));
    for (int c = 0; c < C_; ++c) {
        size_t idx = ((size_t)b * C_ + c) * N_ + n;
        out[idx] = x2[idx] * cal[c] * sa;
    }
}

extern "C" void kernel_launch(void* const* d_in, const int* in_sizes, int n_in,
                              void* d_out, int out_size, void* d_ws, size_t ws_size,
                              hipStream_t stream) {
    const float* x     = (const float*)d_in[0];
    const float* wqkv  = (const float*)d_in[1];
    const float* bqkv  = (const float*)d_in[2];
    const float* wproj = (const float*)d_in[3];
    const float* bproj = (const float*)d_in[4];
    const float* wpe   = (const float*)d_in[5];
    const float* bpe   = (const float*)d_in[6];
    const float* wfc1  = (const float*)d_in[7];
    const float* wfc2  = (const float*)d_in[8];
    const float* wsa   = (const float*)d_in[9];
    float* out = (float*)d_out;

    char* ws = (char*)d_ws;
    size_t off = 0;
    auto alloc = [&](size_t bytes) {
        char* p = ws + off;
        off += (bytes + 255) & ~(size_t)255;
        return p;
    };
    bf16*  qt    = (bf16*)alloc((size_t)B_ * NH_ * N_ * KD_ * 2);
    bf16*  ktb   = (bf16*)alloc((size_t)B_ * NH_ * N_ * KD_ * 2);
    bf16*  vbuf  = (bf16*)alloc((size_t)B_ * NH_ * HD_ * N_ * 2);
    bf16*  xT    = (bf16*)alloc((size_t)B_ * N_ * C_ * 2);
    float* attnT = (float*)alloc((size_t)B_ * N_ * C_ * 4);
    float* x2    = (float*)alloc((size_t)B_ * C_ * N_ * 4);
    bf16*  wqb   = (bf16*)alloc((size_t)HQKV_ * C_ * 2);
    bf16*  wpb   = (bf16*)alloc((size_t)C_ * C_ * 2);
    float* avg   = (float*)alloc(B_ * C_ * 4);
    float* mxb   = (float*)alloc(B_ * C_ * 4);
    float* cab   = (float*)alloc(B_ * C_ * 4);
    float* sain  = (float*)alloc((size_t)B_ * 2 * N_ * 4);
    bf16*  yT    = xT;  // alias: xT dead after k_qkv completes (stream-ordered)

    k_convw<<<dim3((HQKV_ * C_ + 255) / 256), 256, 0, stream>>>(wqkv, wproj, wqb, wpb);
    k_transpose<<<dim3(64, 4, B_), 256, 0, stream>>>(x, xT);
    k_qkv<<<dim3(64, 8, B_), 256, 0, stream>>>(wqb, xT, bqkv, qt, ktb, vbuf);
    k_attn<<<dim3(64, B_ * NH_), 256, 0, stream>>>(qt, ktb, vbuf, attnT);
    k_pe_add<<<dim3(64, B_), 256, 0, stream>>>(attnT, vbuf, wpe, bpe, yT);
    k_proj<<<dim3(64, 4, B_), 256, 0, stream>>>(wpb, yT, bproj, x, x2);
    k_ca_red<<<dim3(B_ * C_), 256, 0, stream>>>(x2, avg, mxb);
    k_ca_mlp<<<dim3(B_), 256, 0, stream>>>(avg, mxb, wfc1, wfc2, cab);
    k_sa_red<<<dim3(16, B_), 256, 0, stream>>>(x2, cab, sain);
    k_final<<<dim3(16, B_), 256, 0, stream>>>(x2, cab, sain, wsa, out);
}

// Round 4
// 299.996 us; speedup vs baseline: 2.1584x; 1.6616x over previous
//
#include <hip/hip_runtime.h>
#include <hip/hip_bf16.h>

typedef __bf16 bf16;
typedef __bf16 bf16x4 __attribute__((ext_vector_type(4)));
typedef __bf16 bf16x8 __attribute__((ext_vector_type(8)));
typedef float f32x4 __attribute__((ext_vector_type(4)));

#define B_ 4
#define C_ 256
#define NH_ 4
#define KD_ 32
#define HD_ 64
#define N_ 4096
#define HQKV_ 512

// ---------------- weight convert ----------------
__global__ __launch_bounds__(256) void k_convw(const float* wq, const float* wp,
                                               bf16* wqb, bf16* wpb) {
    int i = blockIdx.x * 256 + threadIdx.x;
    if (i < HQKV_ * C_) wqb[i] = (bf16)wq[i];
    if (i < C_ * C_)    wpb[i] = (bf16)wp[i];
}

// ---------------- x (B,C,N) f32 -> xT (B,N,C) bf16 ----------------
__global__ __launch_bounds__(256) void k_transpose(const float* __restrict__ x,
                                                   bf16* __restrict__ xT) {
    __shared__ float tile[64][65];
    int b = blockIdx.z, c0 = blockIdx.y * 64, n0 = blockIdx.x * 64;
    int t = threadIdx.x;
    int lane = t & 63, wv = t >> 6;
    for (int k = 0; k < 16; ++k) {
        int cl = k * 4 + wv;
        tile[cl][lane] = x[((size_t)(b * C_ + c0 + cl)) * N_ + n0 + lane];
    }
    __syncthreads();
    for (int k = 0; k < 16; ++k) {
        int nl = k * 4 + wv;
        xT[((size_t)(b * N_ + n0 + nl)) * C_ + c0 + lane] = (bf16)tile[lane][nl];
    }
}

// ---------------- qkv GEMM: W(512x256) @ xT^T, writes q_t,k_t,(B,NH,N,32) v(B,NH,64,N) ----------------
__global__ __launch_bounds__(256) void k_qkv(const bf16* __restrict__ wqb,
                                             const bf16* __restrict__ xT,
                                             const float* __restrict__ bias,
                                             bf16* __restrict__ qt, bf16* __restrict__ kt,
                                             bf16* __restrict__ vb) {
    int n0 = blockIdx.x * 64, o0 = blockIdx.y * 64, b = blockIdx.z;
    int t = threadIdx.x, w = t >> 6, l = t & 63, lr = l & 15, lg = l >> 4;
    const bf16* arow = wqb + (size_t)(o0 + 16 * w + lr) * C_ + 8 * lg;
    const bf16* brow = xT + ((size_t)b * N_ + n0 + lr) * C_ + 8 * lg;
    f32x4 acc[4];
    f32x4 zz = {0.f, 0.f, 0.f, 0.f};
    acc[0] = zz; acc[1] = zz; acc[2] = zz; acc[3] = zz;
    for (int kk = 0; kk < C_; kk += 32) {
        bf16x8 a = *(const bf16x8*)(arow + kk);
#pragma unroll
        for (int tt = 0; tt < 4; ++tt) {
            bf16x8 bb = *(const bf16x8*)(brow + (size_t)tt * 16 * C_ + kk);
            acc[tt] = __builtin_amdgcn_mfma_f32_16x16x32_bf16(a, bb, acc[tt], 0, 0, 0);
        }
    }
    // KD^-0.5 * log2(e) folded into q so attention can use raw exp2
    const float scale = 0.25506953076085663f;
#pragma unroll
    for (int tt = 0; tt < 4; ++tt) {
        int n = n0 + 16 * tt + lr;
#pragma unroll
        for (int j = 0; j < 4; ++j) {
            int o = o0 + 16 * w + 4 * lg + j;
            float val = acc[tt][j] + bias[o];
            int h = o >> 7, r = o & 127;
            size_t bh = (size_t)(b * NH_ + h);
            if (r < KD_)            qt[(bh * N_ + n) * KD_ + r] = (bf16)(val * scale);
            else if (r < 2 * KD_)   kt[(bh * N_ + n) * KD_ + (r - KD_)] = (bf16)val;
            else                    vb[(bh * HD_ + (r - 2 * KD_)) * N_ + n] = (bf16)val;
        }
    }
}

// ---------------- fused flash attention, LDS-staged K/V shared by 4 waves ----------------
// QBLK=32 q-rows per wave (2 Q frags), 128 per block. K/V double-buffered in LDS,
// reg-staged with XOR slot swizzle (write & read sides). One barrier per m-tile.
__global__ __launch_bounds__(256) void k_attn(const bf16* __restrict__ qt,
                                              const bf16* __restrict__ kt,
                                              const bf16* __restrict__ vb,
                                              float* __restrict__ attnT) {
    __shared__ bf16 ldsK[2][64 * KD_];   // [m][k], 64B rows, slot(16B) ^= row&3
    __shared__ bf16 ldsV[2][64 * 64];    // [d][m], 128B rows, slot(16B) ^= row&7
    __shared__ bf16 ldsP[4][32 * 72];    // per-wave P tile [n][m], pad 72
    int n0 = blockIdx.x * 128;
    int bh = blockIdx.y;  // b*NH + h
    int b = bh >> 2, h = bh & 3;
    int t = threadIdx.x, w = t >> 6, l = t & 63, lr = l & 15, lg = l >> 4;

    // Q fragments (B-operand): cols n = n0 + 32w + 16q + lr
    bf16x8 aq0 = *(const bf16x8*)(qt + ((size_t)bh * N_ + n0 + 32 * w + lr) * KD_ + 8 * lg);
    bf16x8 aq1 = *(const bf16x8*)(qt + ((size_t)bh * N_ + n0 + 32 * w + 16 + lr) * KD_ + 8 * lg);

    // staging: wave w owns K rows [16w,16w+16), V rows [16w,16w+16)
    int krow = 16 * w + (l >> 2);
    const bf16* kg = kt + ((size_t)bh * N_ + krow) * KD_ + 8 * (l & 3);
    bf16* kwp = &ldsK[0][0] + krow * KD_ + 8 * ((l & 3) ^ (krow & 3));
    int vrow0 = 16 * w + (l >> 3);
    int vrow1 = vrow0 + 8;
    const bf16* vg0 = vb + ((size_t)bh * HD_ + vrow0) * N_ + 8 * (l & 7);
    const bf16* vg1 = vb + ((size_t)bh * HD_ + vrow1) * N_ + 8 * (l & 7);
    bf16* vwp0 = &ldsV[0][0] + vrow0 * 64 + 8 * ((l & 7) ^ (vrow0 & 7));
    bf16* vwp1 = &ldsV[0][0] + vrow1 * 64 + 8 * ((l & 7) ^ (vrow1 & 7));

    f32x4 zz = {0.f, 0.f, 0.f, 0.f};
    f32x4 Lacc0 = zz, Lacc1 = zz;
    f32x4 oacc[2][4];
#pragma unroll
    for (int q = 0; q < 2; ++q)
#pragma unroll
        for (int dt = 0; dt < 4; ++dt) oacc[q][dt] = zz;
    bf16* myp = &ldsP[w][0];

    // prologue: load tile 0 into regs
    bf16x8 rk = *(const bf16x8*)(kg);
    bf16x8 rv0 = *(const bf16x8*)(vg0);
    bf16x8 rv1 = *(const bf16x8*)(vg1);

    int cur = 0;
    for (int m0 = 0; m0 < N_; m0 += 64) {
        // write staged regs into buf[cur]
        *(bf16x8*)(kwp + cur * (64 * KD_)) = rk;
        *(bf16x8*)(vwp0 + cur * (64 * 64)) = rv0;
        *(bf16x8*)(vwp1 + cur * (64 * 64)) = rv1;
        // issue next-tile loads (land during compute phase)
        if (m0 + 64 < N_) {
            rk  = *(const bf16x8*)(kg + (size_t)(m0 + 64) * KD_);
            rv0 = *(const bf16x8*)(vg0 + m0 + 64);
            rv1 = *(const bf16x8*)(vg1 + m0 + 64);
        }
        __syncthreads();
        const bf16* kb_ = &ldsK[cur][0];
        const bf16* vb_ = &ldsV[cur][0];
        // QK^T (swapped): s[q][tt] = mfma(K, Q)
        f32x4 s0[4], s1[4];
#pragma unroll
        for (int tt = 0; tt < 4; ++tt) {
            bf16x8 kf = *(const bf16x8*)(kb_ + (16 * tt + lr) * KD_ + 8 * (lg ^ (lr & 3)));
            s0[tt] = __builtin_amdgcn_mfma_f32_16x16x32_bf16(kf, aq0, zz, 0, 0, 0);
            s1[tt] = __builtin_amdgcn_mfma_f32_16x16x32_bf16(kf, aq1, zz, 0, 0, 0);
        }
        // exp + P write (per-wave LDS, no barrier)
#pragma unroll
        for (int tt = 0; tt < 4; ++tt) {
            bf16x4 p0, p1;
#pragma unroll
            for (int j = 0; j < 4; ++j) {
                float pv0 = __builtin_amdgcn_exp2f(s0[tt][j]);
                float pv1 = __builtin_amdgcn_exp2f(s1[tt][j]);
                Lacc0[j] += pv0; Lacc1[j] += pv1;
                p0[j] = (bf16)pv0; p1[j] = (bf16)pv1;
            }
            *(bf16x4*)(myp + lr * 72 + 16 * tt + 4 * lg) = p0;
            *(bf16x4*)(myp + (16 + lr) * 72 + 16 * tt + 4 * lg) = p1;
        }
        // PV
#pragma unroll
        for (int ks = 0; ks < 2; ++ks) {
            bf16x8 pa0 = *(const bf16x8*)(myp + lr * 72 + 32 * ks + 8 * lg);
            bf16x8 pa1 = *(const bf16x8*)(myp + (16 + lr) * 72 + 32 * ks + 8 * lg);
#pragma unroll
            for (int dt = 0; dt < 4; ++dt) {
                bf16x8 vf = *(const bf16x8*)(vb_ + (16 * dt + lr) * 64 + 8 * ((4 * ks + lg) ^ (lr & 7)));
                oacc[0][dt] = __builtin_amdgcn_mfma_f32_16x16x32_bf16(pa0, vf, oacc[0][dt], 0, 0, 0);
                oacc[1][dt] = __builtin_amdgcn_mfma_f32_16x16x32_bf16(pa1, vf, oacc[1][dt], 0, 0, 0);
            }
        }
        cur ^= 1;
    }
    // L reduction per n-frag (n = n0+32w+16q+lr), then normalize + write
    float Lp0 = Lacc0[0] + Lacc0[1] + Lacc0[2] + Lacc0[3];
    float Lp1 = Lacc1[0] + Lacc1[1] + Lacc1[2] + Lacc1[3];
    Lp0 += __shfl_xor(Lp0, 16); Lp0 += __shfl_xor(Lp0, 32);
    Lp1 += __shfl_xor(Lp1, 16); Lp1 += __shfl_xor(Lp1, 32);
    float inv0[4], inv1[4];
#pragma unroll
    for (int j = 0; j < 4; ++j) {
        inv0[j] = 1.f / __shfl(Lp0, 4 * lg + j);
        inv1[j] = 1.f / __shfl(Lp1, 4 * lg + j);
    }
#pragma unroll
    for (int dt = 0; dt < 4; ++dt)
#pragma unroll
        for (int j = 0; j < 4; ++j) {
            int n = n0 + 32 * w + 4 * lg + j;
            int d = h * HD_ + 16 * dt + lr;
            attnT[((size_t)b * N_ + n) * C_ + d] = oacc[0][dt][j] * inv0[j];
            attnT[((size_t)b * N_ + n + 16) * C_ + d] = oacc[1][dt][j] * inv1[j];
        }
}

// ---------------- y = attn + dwconv3(v)+b_pe; writes yT (B,N,C) bf16 ----------------
__global__ __launch_bounds__(256) void k_pe_add(const float* __restrict__ attnT,
                                                const bf16* __restrict__ vb,
                                                const float* __restrict__ wpe,
                                                const float* __restrict__ bpe,
                                                bf16* __restrict__ yT) {
    __shared__ float tile[64 * 257];
    int hh = blockIdx.x, b = blockIdx.y;
    int t = threadIdx.x;
    for (int k = 0; k < 64; ++k)
        tile[k * 257 + t] = attnT[((size_t)b * N_ + hh * 64 + k) * C_ + t];
    __syncthreads();
    int ww = t & 63, cg = t >> 6;
    for (int ci = 0; ci < 64; ++ci) {
        int c = cg * 64 + ci;
        const bf16* vrow = vb + (size_t)(b * C_ + c) * N_;
        float acc = bpe[c];
#pragma unroll
        for (int kh = 0; kh < 3; ++kh) {
            int hh2 = hh + kh - 1;
            if (hh2 < 0 || hh2 >= 64) continue;
#pragma unroll
            for (int kw = 0; kw < 3; ++kw) {
                int ww2 = ww + kw - 1;
                if (ww2 < 0 || ww2 >= 64) continue;
                acc += (float)vrow[hh2 * 64 + ww2] * wpe[c * 9 + kh * 3 + kw];
            }
        }
        tile[ww * 257 + c] += acc;
    }
    __syncthreads();
    for (int k = 0; k < 64; ++k)
        yT[((size_t)b * N_ + hh * 64 + k) * C_ + t] = (bf16)tile[k * 257 + t];
}

// ---------------- proj GEMM + residual: x2 = x + Wp @ y + b ----------------
__global__ __launch_bounds__(256) void k_proj(const bf16* __restrict__ wpb,
                                              const bf16* __restrict__ yT,
                                              const float* __restrict__ bias,
                                              const float* __restrict__ x,
                                              float* __restrict__ x2) {
    int n0 = blockIdx.x * 64, o0 = blockIdx.y * 64, b = blockIdx.z;
    int t = threadIdx.x, w = t >> 6, l = t & 63, lr = l & 15, lg = l >> 4;
    const bf16* arow = wpb + (size_t)(o0 + 16 * w + lr) * C_ + 8 * lg;
    const bf16* brow = yT + ((size_t)b * N_ + n0 + lr) * C_ + 8 * lg;
    f32x4 acc[4];
    f32x4 zz = {0.f, 0.f, 0.f, 0.f};
    acc[0] = zz; acc[1] = zz; acc[2] = zz; acc[3] = zz;
    for (int kk = 0; kk < C_; kk += 32) {
        bf16x8 a = *(const bf16x8*)(arow + kk);
#pragma unroll
        for (int tt = 0; tt < 4; ++tt) {
            bf16x8 bb = *(const bf16x8*)(brow + (size_t)tt * 16 * C_ + kk);
            acc[tt] = __builtin_amdgcn_mfma_f32_16x16x32_bf16(a, bb, acc[tt], 0, 0, 0);
        }
    }
#pragma unroll
    for (int tt = 0; tt < 4; ++tt) {
        int n = n0 + 16 * tt + lr;
#pragma unroll
        for (int j = 0; j < 4; ++j) {
            int o = o0 + 16 * w + 4 * lg + j;
            size_t idx = ((size_t)b * C_ + o) * N_ + n;
            x2[idx] = x[idx] + acc[tt][j] + bias[o];
        }
    }
}

// ---------------- channel attention: reduce ----------------
__global__ __launch_bounds__(256) void k_ca_red(const float* __restrict__ x2,
                                                float* __restrict__ avg, float* __restrict__ mx) {
    int bc = blockIdx.x;
    int t = threadIdx.x;
    const float* row = x2 + (size_t)bc * N_;
    float s = 0.f, m = -1e30f;
    for (int i = t; i < N_; i += 256) { float v = row[i]; s += v; m = fmaxf(m, v); }
#pragma unroll
    for (int d = 1; d < 64; d <<= 1) { s += __shfl_xor(s, d); m = fmaxf(m, __shfl_xor(m, d)); }
    __shared__ float ss[4], sm[4];
    int w = t >> 6;
    if ((t & 63) == 0) { ss[w] = s; sm[w] = m; }
    __syncthreads();
    if (t == 0) {
        avg[bc] = (ss[0] + ss[1] + ss[2] + ss[3]) / (float)N_;
        mx[bc] = fmaxf(fmaxf(sm[0], sm[1]), fmaxf(sm[2], sm[3]));
    }
}

// ---------------- channel attention: MLP ----------------
__global__ __launch_bounds__(256) void k_ca_mlp(const float* __restrict__ avg,
                                                const float* __restrict__ mx,
                                                const float* __restrict__ wfc1,
                                                const float* __restrict__ wfc2,
                                                float* __restrict__ ca) {
    int b = blockIdx.x, t = threadIdx.x;
    __shared__ float hsum[16];
    if (t < 16) {
        const float* w1 = wfc1 + t * C_;
        float ha = 0.f, hm = 0.f;
        for (int c = 0; c < C_; ++c) { ha += avg[b * C_ + c] * w1[c]; hm += mx[b * C_ + c] * w1[c]; }
        hsum[t] = fmaxf(ha, 0.f) + fmaxf(hm, 0.f);
    }
    __syncthreads();
    float o = 0.f;
    const float* w2 = wfc2 + t * 16;
#pragma unroll
    for (int r = 0; r < 16; ++r) o += hsum[r] * w2[r];
    ca[b * C_ + t] = 1.f / (1.f + __expf(-o));
}

// ---------------- spatial attention: channel reduce of x2*ca ----------------
__global__ __launch_bounds__(256) void k_sa_red(const float* __restrict__ x2,
                                                const float* __restrict__ ca,
                                                float* __restrict__ sain) {
    int b = blockIdx.y;
    int n = blockIdx.x * 256 + threadIdx.x;
    __shared__ float cal[C_];
    cal[threadIdx.x] = ca[b * C_ + threadIdx.x];
    __syncthreads();
    float s = 0.f, m = -1e30f;
    for (int c = 0; c < C_; ++c) {
        float v = x2[((size_t)b * C_ + c) * N_ + n] * cal[c];
        s += v; m = fmaxf(m, v);
    }
    sain[((size_t)b * 2 + 0) * N_ + n] = s * (1.f / C_);
    sain[((size_t)b * 2 + 1) * N_ + n] = m;
}

// ---------------- final: sa conv + sigmoid + output (f32) ----------------
__global__ __launch_bounds__(256) void k_final(const float* __restrict__ x2,
                                               const float* __restrict__ ca,
                                               const float* __restrict__ sain,
                                               const float* __restrict__ wsa,
                                               float* __restrict__ out) {
    int b = blockIdx.y;
    int n = blockIdx.x * 256 + threadIdx.x;
    __shared__ float cal[C_];
    cal[threadIdx.x] = ca[b * C_ + threadIdx.x];
    __syncthreads();
    int hh = n >> 6, ww = n & 63;
    float acc = 0.f;
#pragma unroll
    for (int i = 0; i < 2; ++i)
#pragma unroll
        for (int kh = 0; kh < 3; ++kh) {
            int hh2 = hh + kh - 1;
            if (hh2 < 0 || hh2 >= 64) continue;
#pragma unroll
            for (int kw = 0; kw < 3; ++kw) {
                int ww2 = ww + kw - 1;
                if (ww2 < 0 || ww2 >= 64) continue;
                acc += sain[((size_t)b * 2 + i) * N_ + hh2 * 64 + ww2] * wsa[i * 9 + kh * 3 + kw];
            }
        }
    float sa = 1.f / (1.f + __expf(-acc));
    for (int c = 0; c < C_; ++c) {
        size_t idx = ((size_t)b * C_ + c) * N_ + n;
        out[idx] = x2[idx] * cal[c] * sa;
    }
}

extern "C" void kernel_launch(void* const* d_in, const int* in_sizes, int n_in,
                              void* d_out, int out_size, void* d_ws, size_t ws_size,
                              hipStream_t stream) {
    const float* x     = (const float*)d_in[0];
    const float* wqkv  = (const float*)d_in[1];
    const float* bqkv  = (const float*)d_in[2];
    const float* wproj = (const float*)d_in[3];
    const float* bproj = (const float*)d_in[4];
    const float* wpe   = (const float*)d_in[5];
    const float* bpe   = (const float*)d_in[6];
    const float* wfc1  = (const float*)d_in[7];
    const float* wfc2  = (const float*)d_in[8];
    const float* wsa   = (const float*)d_in[9];
    float* out = (float*)d_out;

    char* ws = (char*)d_ws;
    size_t off = 0;
    auto alloc = [&](size_t bytes) {
        char* p = ws + off;
        off += (bytes + 255) & ~(size_t)255;
        return p;
    };
    bf16*  qt    = (bf16*)alloc((size_t)B_ * NH_ * N_ * KD_ * 2);
    bf16*  ktb   = (bf16*)alloc((size_t)B_ * NH_ * N_ * KD_ * 2);
    bf16*  vbuf  = (bf16*)alloc((size_t)B_ * NH_ * HD_ * N_ * 2);
    bf16*  xT    = (bf16*)alloc((size_t)B_ * N_ * C_ * 2);
    float* attnT = (float*)alloc((size_t)B_ * N_ * C_ * 4);
    float* x2    = (float*)alloc((size_t)B_ * C_ * N_ * 4);
    bf16*  wqb   = (bf16*)alloc((size_t)HQKV_ * C_ * 2);
    bf16*  wpb   = (bf16*)alloc((size_t)C_ * C_ * 2);
    float* avg   = (float*)alloc(B_ * C_ * 4);
    float* mxb   = (float*)alloc(B_ * C_ * 4);
    float* cab   = (float*)alloc(B_ * C_ * 4);
    float* sain  = (float*)alloc((size_t)B_ * 2 * N_ * 4);
    bf16*  yT    = xT;  // alias: xT dead after k_qkv completes (stream-ordered)

    k_convw<<<dim3((HQKV_ * C_ + 255) / 256), 256, 0, stream>>>(wqkv, wproj, wqb, wpb);
    k_transpose<<<dim3(64, 4, B_), 256, 0, stream>>>(x, xT);
    k_qkv<<<dim3(64, 8, B_), 256, 0, stream>>>(wqb, xT, bqkv, qt, ktb, vbuf);
    k_attn<<<dim3(32, B_ * NH_), 256, 0, stream>>>(qt, ktb, vbuf, attnT);
    k_pe_add<<<dim3(64, B_), 256, 0, stream>>>(attnT, vbuf, wpe, bpe, yT);
    k_proj<<<dim3(64, 4, B_), 256, 0, stream>>>(wpb, yT, bproj, x, x2);
    k_ca_red<<<dim3(B_ * C_), 256, 0, stream>>>(x2, avg, mxb);
    k_ca_mlp<<<dim3(B_), 256, 0, stream>>>(avg, mxb, wfc1, wfc2, cab);
    k_sa_red<<<dim3(16, B_), 256, 0, stream>>>(x2, cab, sain);
    k_final<<<dim3(16, B_), 256, 0, stream>>>(x2, cab, sain, wsa, out);
}

// Round 5
// 233.892 us; speedup vs baseline: 2.7684x; 1.2826x over previous
//
#include <hip/hip_runtime.h>
#include <hip/hip_bf16.h>

typedef __bf16 bf16;
typedef __bf16 bf16x4 __attribute__((ext_vector_type(4)));
typedef __bf16 bf16x8 __attribute__((ext_vector_type(8)));
typedef float f32x4 __attribute__((ext_vector_type(4)));

#define B_ 4
#define C_ 256
#define NH_ 4
#define KD_ 32
#define HD_ 64
#define N_ 4096
#define HQKV_ 512

// ---------------- weight convert ----------------
__global__ __launch_bounds__(256) void k_convw(const float* wq, const float* wp,
                                               bf16* wqb, bf16* wpb) {
    int i = blockIdx.x * 256 + threadIdx.x;
    if (i < HQKV_ * C_) wqb[i] = (bf16)wq[i];
    if (i < C_ * C_)    wpb[i] = (bf16)wp[i];
}

// ---------------- x (B,C,N) f32 -> xT (B,N,C) bf16 ----------------
__global__ __launch_bounds__(256) void k_transpose(const float* __restrict__ x,
                                                   bf16* __restrict__ xT) {
    __shared__ float tile[64][65];
    int b = blockIdx.z, c0 = blockIdx.y * 64, n0 = blockIdx.x * 64;
    int t = threadIdx.x;
    int lane = t & 63, wv = t >> 6;
    for (int k = 0; k < 16; ++k) {
        int cl = k * 4 + wv;
        tile[cl][lane] = x[((size_t)(b * C_ + c0 + cl)) * N_ + n0 + lane];
    }
    __syncthreads();
    for (int k = 0; k < 16; ++k) {
        int nl = k * 4 + wv;
        xT[((size_t)(b * N_ + n0 + nl)) * C_ + c0 + lane] = (bf16)tile[lane][nl];
    }
}

// ---------------- qkv GEMM: W(512x256) @ xT^T, writes q_t,k_t,(B,NH,N,32) v(B,NH,64,N) ----------------
__global__ __launch_bounds__(256) void k_qkv(const bf16* __restrict__ wqb,
                                             const bf16* __restrict__ xT,
                                             const float* __restrict__ bias,
                                             bf16* __restrict__ qt, bf16* __restrict__ kt,
                                             bf16* __restrict__ vb) {
    int n0 = blockIdx.x * 64, o0 = blockIdx.y * 64, b = blockIdx.z;
    int t = threadIdx.x, w = t >> 6, l = t & 63, lr = l & 15, lg = l >> 4;
    const bf16* arow = wqb + (size_t)(o0 + 16 * w + lr) * C_ + 8 * lg;
    const bf16* brow = xT + ((size_t)b * N_ + n0 + lr) * C_ + 8 * lg;
    f32x4 acc[4];
    f32x4 zz = {0.f, 0.f, 0.f, 0.f};
    acc[0] = zz; acc[1] = zz; acc[2] = zz; acc[3] = zz;
    for (int kk = 0; kk < C_; kk += 32) {
        bf16x8 a = *(const bf16x8*)(arow + kk);
#pragma unroll
        for (int tt = 0; tt < 4; ++tt) {
            bf16x8 bb = *(const bf16x8*)(brow + (size_t)tt * 16 * C_ + kk);
            acc[tt] = __builtin_amdgcn_mfma_f32_16x16x32_bf16(a, bb, acc[tt], 0, 0, 0);
        }
    }
    // KD^-0.5 * log2(e) folded into q so attention can use raw exp2
    const float scale = 0.25506953076085663f;
#pragma unroll
    for (int tt = 0; tt < 4; ++tt) {
        int n = n0 + 16 * tt + lr;
#pragma unroll
        for (int j = 0; j < 4; ++j) {
            int o = o0 + 16 * w + 4 * lg + j;
            float val = acc[tt][j] + bias[o];
            int h = o >> 7, r = o & 127;
            size_t bh = (size_t)(b * NH_ + h);
            if (r < KD_)            qt[(bh * N_ + n) * KD_ + r] = (bf16)(val * scale);
            else if (r < 2 * KD_)   kt[(bh * N_ + n) * KD_ + (r - KD_)] = (bf16)val;
            else                    vb[(bh * HD_ + (r - 2 * KD_)) * N_ + n] = (bf16)val;
        }
    }
}

// ---------------- fused flash attention, LDS-staged K/V shared by 4 waves ----------------
__global__ __launch_bounds__(256) void k_attn(const bf16* __restrict__ qt,
                                              const bf16* __restrict__ kt,
                                              const bf16* __restrict__ vb,
                                              float* __restrict__ attnT) {
    __shared__ bf16 ldsK[2][64 * KD_];   // [m][k], 64B rows, slot(16B) ^= row&3
    __shared__ bf16 ldsV[2][64 * 64];    // [d][m], 128B rows, slot(16B) ^= row&7
    __shared__ bf16 ldsP[4][32 * 72];    // per-wave P tile [n][m], pad 72
    int n0 = blockIdx.x * 128;
    int bh = blockIdx.y;  // b*NH + h
    int b = bh >> 2, h = bh & 3;
    int t = threadIdx.x, w = t >> 6, l = t & 63, lr = l & 15, lg = l >> 4;

    bf16x8 aq0 = *(const bf16x8*)(qt + ((size_t)bh * N_ + n0 + 32 * w + lr) * KD_ + 8 * lg);
    bf16x8 aq1 = *(const bf16x8*)(qt + ((size_t)bh * N_ + n0 + 32 * w + 16 + lr) * KD_ + 8 * lg);

    int krow = 16 * w + (l >> 2);
    const bf16* kg = kt + ((size_t)bh * N_ + krow) * KD_ + 8 * (l & 3);
    bf16* kwp = &ldsK[0][0] + krow * KD_ + 8 * ((l & 3) ^ (krow & 3));
    int vrow0 = 16 * w + (l >> 3);
    int vrow1 = vrow0 + 8;
    const bf16* vg0 = vb + ((size_t)bh * HD_ + vrow0) * N_ + 8 * (l & 7);
    const bf16* vg1 = vb + ((size_t)bh * HD_ + vrow1) * N_ + 8 * (l & 7);
    bf16* vwp0 = &ldsV[0][0] + vrow0 * 64 + 8 * ((l & 7) ^ (vrow0 & 7));
    bf16* vwp1 = &ldsV[0][0] + vrow1 * 64 + 8 * ((l & 7) ^ (vrow1 & 7));

    f32x4 zz = {0.f, 0.f, 0.f, 0.f};
    f32x4 Lacc0 = zz, Lacc1 = zz;
    f32x4 oacc[2][4];
#pragma unroll
    for (int q = 0; q < 2; ++q)
#pragma unroll
        for (int dt = 0; dt < 4; ++dt) oacc[q][dt] = zz;
    bf16* myp = &ldsP[w][0];

    bf16x8 rk = *(const bf16x8*)(kg);
    bf16x8 rv0 = *(const bf16x8*)(vg0);
    bf16x8 rv1 = *(const bf16x8*)(vg1);

    int cur = 0;
    for (int m0 = 0; m0 < N_; m0 += 64) {
        *(bf16x8*)(kwp + cur * (64 * KD_)) = rk;
        *(bf16x8*)(vwp0 + cur * (64 * 64)) = rv0;
        *(bf16x8*)(vwp1 + cur * (64 * 64)) = rv1;
        if (m0 + 64 < N_) {
            rk  = *(const bf16x8*)(kg + (size_t)(m0 + 64) * KD_);
            rv0 = *(const bf16x8*)(vg0 + m0 + 64);
            rv1 = *(const bf16x8*)(vg1 + m0 + 64);
        }
        __syncthreads();
        const bf16* kb_ = &ldsK[cur][0];
        const bf16* vb_ = &ldsV[cur][0];
        f32x4 s0[4], s1[4];
#pragma unroll
        for (int tt = 0; tt < 4; ++tt) {
            bf16x8 kf = *(const bf16x8*)(kb_ + (16 * tt + lr) * KD_ + 8 * (lg ^ (lr & 3)));
            s0[tt] = __builtin_amdgcn_mfma_f32_16x16x32_bf16(kf, aq0, zz, 0, 0, 0);
            s1[tt] = __builtin_amdgcn_mfma_f32_16x16x32_bf16(kf, aq1, zz, 0, 0, 0);
        }
#pragma unroll
        for (int tt = 0; tt < 4; ++tt) {
            bf16x4 p0, p1;
#pragma unroll
            for (int j = 0; j < 4; ++j) {
                float pv0 = __builtin_amdgcn_exp2f(s0[tt][j]);
                float pv1 = __builtin_amdgcn_exp2f(s1[tt][j]);
                Lacc0[j] += pv0; Lacc1[j] += pv1;
                p0[j] = (bf16)pv0; p1[j] = (bf16)pv1;
            }
            *(bf16x4*)(myp + lr * 72 + 16 * tt + 4 * lg) = p0;
            *(bf16x4*)(myp + (16 + lr) * 72 + 16 * tt + 4 * lg) = p1;
        }
#pragma unroll
        for (int ks = 0; ks < 2; ++ks) {
            bf16x8 pa0 = *(const bf16x8*)(myp + lr * 72 + 32 * ks + 8 * lg);
            bf16x8 pa1 = *(const bf16x8*)(myp + (16 + lr) * 72 + 32 * ks + 8 * lg);
#pragma unroll
            for (int dt = 0; dt < 4; ++dt) {
                bf16x8 vf = *(const bf16x8*)(vb_ + (16 * dt + lr) * 64 + 8 * ((4 * ks + lg) ^ (lr & 7)));
                oacc[0][dt] = __builtin_amdgcn_mfma_f32_16x16x32_bf16(pa0, vf, oacc[0][dt], 0, 0, 0);
                oacc[1][dt] = __builtin_amdgcn_mfma_f32_16x16x32_bf16(pa1, vf, oacc[1][dt], 0, 0, 0);
            }
        }
        cur ^= 1;
    }
    float Lp0 = Lacc0[0] + Lacc0[1] + Lacc0[2] + Lacc0[3];
    float Lp1 = Lacc1[0] + Lacc1[1] + Lacc1[2] + Lacc1[3];
    Lp0 += __shfl_xor(Lp0, 16); Lp0 += __shfl_xor(Lp0, 32);
    Lp1 += __shfl_xor(Lp1, 16); Lp1 += __shfl_xor(Lp1, 32);
    float inv0[4], inv1[4];
#pragma unroll
    for (int j = 0; j < 4; ++j) {
        inv0[j] = 1.f / __shfl(Lp0, 4 * lg + j);
        inv1[j] = 1.f / __shfl(Lp1, 4 * lg + j);
    }
#pragma unroll
    for (int dt = 0; dt < 4; ++dt)
#pragma unroll
        for (int j = 0; j < 4; ++j) {
            int n = n0 + 32 * w + 4 * lg + j;
            int d = h * HD_ + 16 * dt + lr;
            attnT[((size_t)b * N_ + n) * C_ + d] = oacc[0][dt][j] * inv0[j];
            attnT[((size_t)b * N_ + n + 16) * C_ + d] = oacc[1][dt][j] * inv1[j];
        }
}

// ---------------- y = attn + dwconv3(v)+b_pe; writes yT (B,N,C) bf16 ----------------
// Parallel rewrite: block = (hh row, 64-channel tile, b); lane = channel.
// v window staged in LDS f32 [c][199] (odd stride -> conflict-free strided reads).
__global__ __launch_bounds__(256) void k_pe_add(const float* __restrict__ attnT,
                                                const bf16* __restrict__ vb,
                                                const float* __restrict__ wpe,
                                                const float* __restrict__ bpe,
                                                bf16* __restrict__ yT) {
    __shared__ float vt[64 * 199];  // [c_local][kh*66 + wslot], wslot = w+1, pads at 0 and 65
    int hh = blockIdx.x, c0 = blockIdx.y * 64, b = blockIdx.z;
    int t = threadIdx.x, lane = t & 63, wg = t >> 6;

    // zero the w-pad slots
    if (t < 192) {
        int c_l = t >> 2, kh2 = t & 3;
        if (kh2 < 3) {
            vt[c_l * 199 + kh2 * 66 + 0] = 0.f;
            vt[c_l * 199 + kh2 * 66 + 65] = 0.f;
        }
    }
    if (t >= 192) {  // cover c_l 48..63 pads
        int u = t - 192;
        int c_l = 48 + (u >> 2), kh2 = u & 3;
        if (kh2 < 3) {
            vt[c_l * 199 + kh2 * 66 + 0] = 0.f;
            vt[c_l * 199 + kh2 * 66 + 65] = 0.f;
        }
    }
    // stage v rows hh-1..hh+1 for 64 channels; lanes = w (coalesced 128B)
#pragma unroll
    for (int kh = 0; kh < 3; ++kh) {
        int hh2 = hh + kh - 1;
        bool ok = (hh2 >= 0 && hh2 < 64);
        for (int ci = 0; ci < 16; ++ci) {
            int c_l = wg * 16 + ci;
            float val = ok ? (float)vb[((size_t)(b * C_ + c0 + c_l)) * N_ + hh2 * 64 + lane] : 0.f;
            vt[c_l * 199 + kh * 66 + 1 + lane] = val;
        }
    }
    __syncthreads();

    // per-thread channel = c0 + lane; 9 taps + bias in registers
    int c = c0 + lane;
    float w9[9];
#pragma unroll
    for (int k = 0; k < 9; ++k) w9[k] = wpe[c * 9 + k];
    float bc = bpe[c];
    const float* vrow = vt + lane * 199;

#pragma unroll
    for (int wi = 0; wi < 16; ++wi) {
        int w = wg * 16 + wi;
        float acc = bc;
#pragma unroll
        for (int kh = 0; kh < 3; ++kh)
#pragma unroll
            for (int kw = 0; kw < 3; ++kw)
                acc += vrow[kh * 66 + w + kw] * w9[kh * 3 + kw];
        int n = hh * 64 + w;
        size_t idx = ((size_t)b * N_ + n) * C_ + c;
        yT[idx] = (bf16)(attnT[idx] + acc);
    }
}

// ---------------- proj GEMM + residual: x2 = x + Wp @ y + b ----------------
__global__ __launch_bounds__(256) void k_proj(const bf16* __restrict__ wpb,
                                              const bf16* __restrict__ yT,
                                              const float* __restrict__ bias,
                                              const float* __restrict__ x,
                                              float* __restrict__ x2) {
    int n0 = blockIdx.x * 64, o0 = blockIdx.y * 64, b = blockIdx.z;
    int t = threadIdx.x, w = t >> 6, l = t & 63, lr = l & 15, lg = l >> 4;
    const bf16* arow = wpb + (size_t)(o0 + 16 * w + lr) * C_ + 8 * lg;
    const bf16* brow = yT + ((size_t)b * N_ + n0 + lr) * C_ + 8 * lg;
    f32x4 acc[4];
    f32x4 zz = {0.f, 0.f, 0.f, 0.f};
    acc[0] = zz; acc[1] = zz; acc[2] = zz; acc[3] = zz;
    for (int kk = 0; kk < C_; kk += 32) {
        bf16x8 a = *(const bf16x8*)(arow + kk);
#pragma unroll
        for (int tt = 0; tt < 4; ++tt) {
            bf16x8 bb = *(const bf16x8*)(brow + (size_t)tt * 16 * C_ + kk);
            acc[tt] = __builtin_amdgcn_mfma_f32_16x16x32_bf16(a, bb, acc[tt], 0, 0, 0);
        }
    }
#pragma unroll
    for (int tt = 0; tt < 4; ++tt) {
        int n = n0 + 16 * tt + lr;
#pragma unroll
        for (int j = 0; j < 4; ++j) {
            int o = o0 + 16 * w + 4 * lg + j;
            size_t idx = ((size_t)b * C_ + o) * N_ + n;
            x2[idx] = x[idx] + acc[tt][j] + bias[o];
        }
    }
}

// ---------------- channel attention: reduce ----------------
__global__ __launch_bounds__(256) void k_ca_red(const float* __restrict__ x2,
                                                float* __restrict__ avg, float* __restrict__ mx) {
    int bc = blockIdx.x;
    int t = threadIdx.x;
    const float* row = x2 + (size_t)bc * N_;
    float s = 0.f, m = -1e30f;
    for (int i = t; i < N_; i += 256) { float v = row[i]; s += v; m = fmaxf(m, v); }
#pragma unroll
    for (int d = 1; d < 64; d <<= 1) { s += __shfl_xor(s, d); m = fmaxf(m, __shfl_xor(m, d)); }
    __shared__ float ss[4], sm[4];
    int w = t >> 6;
    if ((t & 63) == 0) { ss[w] = s; sm[w] = m; }
    __syncthreads();
    if (t == 0) {
        avg[bc] = (ss[0] + ss[1] + ss[2] + ss[3]) / (float)N_;
        mx[bc] = fmaxf(fmaxf(sm[0], sm[1]), fmaxf(sm[2], sm[3]));
    }
}

// ---------------- channel attention: MLP ----------------
__global__ __launch_bounds__(256) void k_ca_mlp(const float* __restrict__ avg,
                                                const float* __restrict__ mx,
                                                const float* __restrict__ wfc1,
                                                const float* __restrict__ wfc2,
                                                float* __restrict__ ca) {
    int b = blockIdx.x, t = threadIdx.x;
    __shared__ float hsum[16];
    if (t < 16) {
        const float* w1 = wfc1 + t * C_;
        float ha = 0.f, hm = 0.f;
        for (int c = 0; c < C_; ++c) { ha += avg[b * C_ + c] * w1[c]; hm += mx[b * C_ + c] * w1[c]; }
        hsum[t] = fmaxf(ha, 0.f) + fmaxf(hm, 0.f);
    }
    __syncthreads();
    float o = 0.f;
    const float* w2 = wfc2 + t * 16;
#pragma unroll
    for (int r = 0; r < 16; ++r) o += hsum[r] * w2[r];
    ca[b * C_ + t] = 1.f / (1.f + __expf(-o));
}

// ---------------- spatial attention: channel reduce of x2*ca ----------------
__global__ __launch_bounds__(256) void k_sa_red(const float* __restrict__ x2,
                                                const float* __restrict__ ca,
                                                float* __restrict__ sain) {
    int b = blockIdx.y;
    int n = blockIdx.x * 256 + threadIdx.x;
    __shared__ float cal[C_];
    cal[threadIdx.x] = ca[b * C_ + threadIdx.x];
    __syncthreads();
    float s = 0.f, m = -1e30f;
    for (int c = 0; c < C_; ++c) {
        float v = x2[((size_t)b * C_ + c) * N_ + n] * cal[c];
        s += v; m = fmaxf(m, v);
    }
    sain[((size_t)b * 2 + 0) * N_ + n] = s * (1.f / C_);
    sain[((size_t)b * 2 + 1) * N_ + n] = m;
}

// ---------------- final: sa conv + sigmoid + output (f32) ----------------
__global__ __launch_bounds__(256) void k_final(const float* __restrict__ x2,
                                               const float* __restrict__ ca,
                                               const float* __restrict__ sain,
                                               const float* __restrict__ wsa,
                                               float* __restrict__ out) {
    int b = blockIdx.y;
    int n = blockIdx.x * 256 + threadIdx.x;
    __shared__ float cal[C_];
    cal[threadIdx.x] = ca[b * C_ + threadIdx.x];
    __syncthreads();
    int hh = n >> 6, ww = n & 63;
    float acc = 0.f;
#pragma unroll
    for (int i = 0; i < 2; ++i)
#pragma unroll
        for (int kh = 0; kh < 3; ++kh) {
            int hh2 = hh + kh - 1;
            if (hh2 < 0 || hh2 >= 64) continue;
#pragma unroll
            for (int kw = 0; kw < 3; ++kw) {
                int ww2 = ww + kw - 1;
                if (ww2 < 0 || ww2 >= 64) continue;
                acc += sain[((size_t)b * 2 + i) * N_ + hh2 * 64 + ww2] * wsa[i * 9 + kh * 3 + kw];
            }
        }
    float sa = 1.f / (1.f + __expf(-acc));
    for (int c = 0; c < C_; ++c) {
        size_t idx = ((size_t)b * C_ + c) * N_ + n;
        out[idx] = x2[idx] * cal[c] * sa;
    }
}

extern "C" void kernel_launch(void* const* d_in, const int* in_sizes, int n_in,
                              void* d_out, int out_size, void* d_ws, size_t ws_size,
                              hipStream_t stream) {
    const float* x     = (const float*)d_in[0];
    const float* wqkv  = (const float*)d_in[1];
    const float* bqkv  = (const float*)d_in[2];
    const float* wproj = (const float*)d_in[3];
    const float* bproj = (const float*)d_in[4];
    const float* wpe   = (const float*)d_in[5];
    const float* bpe   = (const float*)d_in[6];
    const float* wfc1  = (const float*)d_in[7];
    const float* wfc2  = (const float*)d_in[8];
    const float* wsa   = (const float*)d_in[9];
    float* out = (float*)d_out;

    char* ws = (char*)d_ws;
    size_t off = 0;
    auto alloc = [&](size_t bytes) {
        char* p = ws + off;
        off += (bytes + 255) & ~(size_t)255;
        return p;
    };
    bf16*  qt    = (bf16*)alloc((size_t)B_ * NH_ * N_ * KD_ * 2);
    bf16*  ktb   = (bf16*)alloc((size_t)B_ * NH_ * N_ * KD_ * 2);
    bf16*  vbuf  = (bf16*)alloc((size_t)B_ * NH_ * HD_ * N_ * 2);
    bf16*  xT    = (bf16*)alloc((size_t)B_ * N_ * C_ * 2);
    float* attnT = (float*)alloc((size_t)B_ * N_ * C_ * 4);
    float* x2    = (float*)alloc((size_t)B_ * C_ * N_ * 4);
    bf16*  wqb   = (bf16*)alloc((size_t)HQKV_ * C_ * 2);
    bf16*  wpb   = (bf16*)alloc((size_t)C_ * C_ * 2);
    float* avg   = (float*)alloc(B_ * C_ * 4);
    float* mxb   = (float*)alloc(B_ * C_ * 4);
    float* cab   = (float*)alloc(B_ * C_ * 4);
    float* sain  = (float*)alloc((size_t)B_ * 2 * N_ * 4);
    bf16*  yT    = xT;  // alias: xT dead after k_qkv completes (stream-ordered)

    k_convw<<<dim3((HQKV_ * C_ + 255) / 256), 256, 0, stream>>>(wqkv, wproj, wqb, wpb);
    k_transpose<<<dim3(64, 4, B_), 256, 0, stream>>>(x, xT);
    k_qkv<<<dim3(64, 8, B_), 256, 0, stream>>>(wqb, xT, bqkv, qt, ktb, vbuf);
    k_attn<<<dim3(32, B_ * NH_), 256, 0, stream>>>(qt, ktb, vbuf, attnT);
    k_pe_add<<<dim3(64, 4, B_), 256, 0, stream>>>(attnT, vbuf, wpe, bpe, yT);
    k_proj<<<dim3(64, 4, B_), 256, 0, stream>>>(wpb, yT, bproj, x, x2);
    k_ca_red<<<dim3(B_ * C_), 256, 0, stream>>>(x2, avg, mxb);
    k_ca_mlp<<<dim3(B_), 256, 0, stream>>>(avg, mxb, wfc1, wfc2, cab);
    k_sa_red<<<dim3(16, B_), 256, 0, stream>>>(x2, cab, sain);
    k_final<<<dim3(16, B_), 256, 0, stream>>>(x2, cab, sain, wsa, out);
}

// Round 6
// 227.581 us; speedup vs baseline: 2.8452x; 1.0277x over previous
//
#include <hip/hip_runtime.h>
#include <hip/hip_bf16.h>

typedef __bf16 bf16;
typedef __bf16 bf16x4 __attribute__((ext_vector_type(4)));
typedef __bf16 bf16x8 __attribute__((ext_vector_type(8)));
typedef float f32x4 __attribute__((ext_vector_type(4)));

#define B_ 4
#define C_ 256
#define NH_ 4
#define KD_ 32
#define HD_ 64
#define N_ 4096
#define HQKV_ 512

// ---------------- weight convert ----------------
__global__ __launch_bounds__(256) void k_convw(const float* wq, const float* wp,
                                               bf16* wqb, bf16* wpb) {
    int i = blockIdx.x * 256 + threadIdx.x;
    if (i < HQKV_ * C_) wqb[i] = (bf16)wq[i];
    if (i < C_ * C_)    wpb[i] = (bf16)wp[i];
}

// ---------------- x (B,C,N) f32 -> xT (B,N,C) bf16 ----------------
__global__ __launch_bounds__(256) void k_transpose(const float* __restrict__ x,
                                                   bf16* __restrict__ xT) {
    __shared__ float tile[64][65];
    int b = blockIdx.z, c0 = blockIdx.y * 64, n0 = blockIdx.x * 64;
    int t = threadIdx.x;
    int lane = t & 63, wv = t >> 6;
    for (int k = 0; k < 16; ++k) {
        int cl = k * 4 + wv;
        tile[cl][lane] = x[((size_t)(b * C_ + c0 + cl)) * N_ + n0 + lane];
    }
    __syncthreads();
    for (int k = 0; k < 16; ++k) {
        int nl = k * 4 + wv;
        xT[((size_t)(b * N_ + n0 + nl)) * C_ + c0 + lane] = (bf16)tile[lane][nl];
    }
}

// ---------------- qkv GEMM: W(512x256) @ xT^T, writes q_t,k_t,(B,NH,N,32) v(B,NH,64,N) ----------------
__global__ __launch_bounds__(256) void k_qkv(const bf16* __restrict__ wqb,
                                             const bf16* __restrict__ xT,
                                             const float* __restrict__ bias,
                                             bf16* __restrict__ qt, bf16* __restrict__ kt,
                                             bf16* __restrict__ vb) {
    int n0 = blockIdx.x * 64, o0 = blockIdx.y * 64, b = blockIdx.z;
    int t = threadIdx.x, w = t >> 6, l = t & 63, lr = l & 15, lg = l >> 4;
    const bf16* arow = wqb + (size_t)(o0 + 16 * w + lr) * C_ + 8 * lg;
    const bf16* brow = xT + ((size_t)b * N_ + n0 + lr) * C_ + 8 * lg;
    f32x4 acc[4];
    f32x4 zz = {0.f, 0.f, 0.f, 0.f};
    acc[0] = zz; acc[1] = zz; acc[2] = zz; acc[3] = zz;
    for (int kk = 0; kk < C_; kk += 32) {
        bf16x8 a = *(const bf16x8*)(arow + kk);
#pragma unroll
        for (int tt = 0; tt < 4; ++tt) {
            bf16x8 bb = *(const bf16x8*)(brow + (size_t)tt * 16 * C_ + kk);
            acc[tt] = __builtin_amdgcn_mfma_f32_16x16x32_bf16(a, bb, acc[tt], 0, 0, 0);
        }
    }
    // KD^-0.5 * log2(e) folded into q so attention can use raw exp2
    const float scale = 0.25506953076085663f;
#pragma unroll
    for (int tt = 0; tt < 4; ++tt) {
        int n = n0 + 16 * tt + lr;
#pragma unroll
        for (int j = 0; j < 4; ++j) {
            int o = o0 + 16 * w + 4 * lg + j;
            float val = acc[tt][j] + bias[o];
            int h = o >> 7, r = o & 127;
            size_t bh = (size_t)(b * NH_ + h);
            if (r < KD_)            qt[(bh * N_ + n) * KD_ + r] = (bf16)(val * scale);
            else if (r < 2 * KD_)   kt[(bh * N_ + n) * KD_ + (r - KD_)] = (bf16)val;
            else                    vb[(bh * HD_ + (r - 2 * KD_)) * N_ + n] = (bf16)val;
        }
    }
}

// ---------------- fused flash attention, dual-tile pipelined, XCD-confined ----------------
// m-step 128 (two 64-row halves a,b). Order: QKa,QKb, expa/Pa, PVa, expb/Pb, PVb.
// K/V double-buffered per iter parity; bh = blockIdx%16 so each XCD keeps 2 heads'
// K/V (2MB) resident in its 4MB L2. P buffer reused a->b (per-wave in-order LDS).
__global__ __launch_bounds__(256) void k_attn(const bf16* __restrict__ qt,
                                              const bf16* __restrict__ kt,
                                              const bf16* __restrict__ vb,
                                              bf16* __restrict__ attnT) {
    __shared__ bf16 ldsK[2][2][64 * KD_];   // [parity][half][m][k], slot ^= row&3
    __shared__ bf16 ldsV[2][2][64 * 64];    // [parity][half][d][m], slot ^= row&7
    __shared__ bf16 ldsP[4][32 * 72];       // per-wave P tile [n][m], pad 72
    int id = blockIdx.x;
    int bh = id & 15;            // id%8 == bh%8 -> head-pair per XCD
    int n0 = (id >> 4) * 128;
    int b = bh >> 2, h = bh & 3;
    int t = threadIdx.x, w = t >> 6, l = t & 63, lr = l & 15, lg = l >> 4;

    bf16x8 aq0 = *(const bf16x8*)(qt + ((size_t)bh * N_ + n0 + 32 * w + lr) * KD_ + 8 * lg);
    bf16x8 aq1 = *(const bf16x8*)(qt + ((size_t)bh * N_ + n0 + 32 * w + 16 + lr) * KD_ + 8 * lg);

    int krow = 16 * w + (l >> 2);
    const bf16* kg = kt + ((size_t)bh * N_ + krow) * KD_ + 8 * (l & 3);
    int kwo = krow * KD_ + 8 * ((l & 3) ^ (krow & 3));
    int vrow0 = 16 * w + (l >> 3), vrow1 = vrow0 + 8;
    const bf16* vg0 = vb + ((size_t)bh * HD_ + vrow0) * N_ + 8 * (l & 7);
    const bf16* vg1 = vb + ((size_t)bh * HD_ + vrow1) * N_ + 8 * (l & 7);
    int vwo0 = vrow0 * 64 + 8 * ((l & 7) ^ (vrow0 & 7));
    int vwo1 = vrow1 * 64 + 8 * ((l & 7) ^ (vrow1 & 7));

    f32x4 zz = {0.f, 0.f, 0.f, 0.f};
    f32x4 Lacc0 = zz, Lacc1 = zz;
    f32x4 oacc[2][4];
#pragma unroll
    for (int q = 0; q < 2; ++q)
#pragma unroll
        for (int dt = 0; dt < 4; ++dt) oacc[q][dt] = zz;
    bf16* myp = &ldsP[w][0];

    // prologue: stage regs for tile 0 (halves a,b)
    bf16x8 rka  = *(const bf16x8*)(kg);
    bf16x8 rkb  = *(const bf16x8*)(kg + (size_t)64 * KD_);
    bf16x8 rva0 = *(const bf16x8*)(vg0);
    bf16x8 rva1 = *(const bf16x8*)(vg1);
    bf16x8 rvb0 = *(const bf16x8*)(vg0 + 64);
    bf16x8 rvb1 = *(const bf16x8*)(vg1 + 64);

    int p = 0;
    for (int m0 = 0; m0 < N_; m0 += 128, p ^= 1) {
        *(bf16x8*)(&ldsK[p][0][0] + kwo)  = rka;
        *(bf16x8*)(&ldsK[p][1][0] + kwo)  = rkb;
        *(bf16x8*)(&ldsV[p][0][0] + vwo0) = rva0;
        *(bf16x8*)(&ldsV[p][0][0] + vwo1) = rva1;
        *(bf16x8*)(&ldsV[p][1][0] + vwo0) = rvb0;
        *(bf16x8*)(&ldsV[p][1][0] + vwo1) = rvb1;
        if (m0 + 128 < N_) {
            rka  = *(const bf16x8*)(kg + (size_t)(m0 + 128) * KD_);
            rkb  = *(const bf16x8*)(kg + (size_t)(m0 + 192) * KD_);
            rva0 = *(const bf16x8*)(vg0 + m0 + 128);
            rva1 = *(const bf16x8*)(vg1 + m0 + 128);
            rvb0 = *(const bf16x8*)(vg0 + m0 + 192);
            rvb1 = *(const bf16x8*)(vg1 + m0 + 192);
        }
        __syncthreads();
        const bf16* ka_ = &ldsK[p][0][0];
        const bf16* kb_ = &ldsK[p][1][0];
        const bf16* va_ = &ldsV[p][0][0];
        const bf16* vb_ = &ldsV[p][1][0];

        f32x4 sa0[4], sa1[4], sb0[4], sb1[4];
        __builtin_amdgcn_s_setprio(1);
#pragma unroll
        for (int tt = 0; tt < 4; ++tt) {
            bf16x8 kf = *(const bf16x8*)(ka_ + (16 * tt + lr) * KD_ + 8 * (lg ^ (lr & 3)));
            sa0[tt] = __builtin_amdgcn_mfma_f32_16x16x32_bf16(kf, aq0, zz, 0, 0, 0);
            sa1[tt] = __builtin_amdgcn_mfma_f32_16x16x32_bf16(kf, aq1, zz, 0, 0, 0);
        }
#pragma unroll
        for (int tt = 0; tt < 4; ++tt) {
            bf16x8 kf = *(const bf16x8*)(kb_ + (16 * tt + lr) * KD_ + 8 * (lg ^ (lr & 3)));
            sb0[tt] = __builtin_amdgcn_mfma_f32_16x16x32_bf16(kf, aq0, zz, 0, 0, 0);
            sb1[tt] = __builtin_amdgcn_mfma_f32_16x16x32_bf16(kf, aq1, zz, 0, 0, 0);
        }
        __builtin_amdgcn_s_setprio(0);
        // exp(a) + write Pa
#pragma unroll
        for (int tt = 0; tt < 4; ++tt) {
            bf16x4 p0, p1;
#pragma unroll
            for (int j = 0; j < 4; ++j) {
                float pv0 = __builtin_amdgcn_exp2f(sa0[tt][j]);
                float pv1 = __builtin_amdgcn_exp2f(sa1[tt][j]);
                Lacc0[j] += pv0; Lacc1[j] += pv1;
                p0[j] = (bf16)pv0; p1[j] = (bf16)pv1;
            }
            *(bf16x4*)(myp + lr * 72 + 16 * tt + 4 * lg) = p0;
            *(bf16x4*)(myp + (16 + lr) * 72 + 16 * tt + 4 * lg) = p1;
        }
        // PVa
        __builtin_amdgcn_s_setprio(1);
#pragma unroll
        for (int ks = 0; ks < 2; ++ks) {
            bf16x8 pa0 = *(const bf16x8*)(myp + lr * 72 + 32 * ks + 8 * lg);
            bf16x8 pa1 = *(const bf16x8*)(myp + (16 + lr) * 72 + 32 * ks + 8 * lg);
#pragma unroll
            for (int dt = 0; dt < 4; ++dt) {
                bf16x8 vf = *(const bf16x8*)(va_ + (16 * dt + lr) * 64 + 8 * ((4 * ks + lg) ^ (lr & 7)));
                oacc[0][dt] = __builtin_amdgcn_mfma_f32_16x16x32_bf16(pa0, vf, oacc[0][dt], 0, 0, 0);
                oacc[1][dt] = __builtin_amdgcn_mfma_f32_16x16x32_bf16(pa1, vf, oacc[1][dt], 0, 0, 0);
            }
        }
        __builtin_amdgcn_s_setprio(0);
        // exp(b) + write Pb (same P buffer; same-address ordering keeps PVa reads first)
#pragma unroll
        for (int tt = 0; tt < 4; ++tt) {
            bf16x4 p0, p1;
#pragma unroll
            for (int j = 0; j < 4; ++j) {
                float pv0 = __builtin_amdgcn_exp2f(sb0[tt][j]);
                float pv1 = __builtin_amdgcn_exp2f(sb1[tt][j]);
                Lacc0[j] += pv0; Lacc1[j] += pv1;
                p0[j] = (bf16)pv0; p1[j] = (bf16)pv1;
            }
            *(bf16x4*)(myp + lr * 72 + 16 * tt + 4 * lg) = p0;
            *(bf16x4*)(myp + (16 + lr) * 72 + 16 * tt + 4 * lg) = p1;
        }
        // PVb
        __builtin_amdgcn_s_setprio(1);
#pragma unroll
        for (int ks = 0; ks < 2; ++ks) {
            bf16x8 pa0 = *(const bf16x8*)(myp + lr * 72 + 32 * ks + 8 * lg);
            bf16x8 pa1 = *(const bf16x8*)(myp + (16 + lr) * 72 + 32 * ks + 8 * lg);
#pragma unroll
            for (int dt = 0; dt < 4; ++dt) {
                bf16x8 vf = *(const bf16x8*)(vb_ + (16 * dt + lr) * 64 + 8 * ((4 * ks + lg) ^ (lr & 7)));
                oacc[0][dt] = __builtin_amdgcn_mfma_f32_16x16x32_bf16(pa0, vf, oacc[0][dt], 0, 0, 0);
                oacc[1][dt] = __builtin_amdgcn_mfma_f32_16x16x32_bf16(pa1, vf, oacc[1][dt], 0, 0, 0);
            }
        }
        __builtin_amdgcn_s_setprio(0);
    }
    float Lp0 = Lacc0[0] + Lacc0[1] + Lacc0[2] + Lacc0[3];
    float Lp1 = Lacc1[0] + Lacc1[1] + Lacc1[2] + Lacc1[3];
    Lp0 += __shfl_xor(Lp0, 16); Lp0 += __shfl_xor(Lp0, 32);
    Lp1 += __shfl_xor(Lp1, 16); Lp1 += __shfl_xor(Lp1, 32);
    float inv0[4], inv1[4];
#pragma unroll
    for (int j = 0; j < 4; ++j) {
        inv0[j] = 1.f / __shfl(Lp0, 4 * lg + j);
        inv1[j] = 1.f / __shfl(Lp1, 4 * lg + j);
    }
#pragma unroll
    for (int dt = 0; dt < 4; ++dt)
#pragma unroll
        for (int j = 0; j < 4; ++j) {
            int n = n0 + 32 * w + 4 * lg + j;
            int d = h * HD_ + 16 * dt + lr;
            attnT[((size_t)b * N_ + n) * C_ + d] = (bf16)(oacc[0][dt][j] * inv0[j]);
            attnT[((size_t)b * N_ + n + 16) * C_ + d] = (bf16)(oacc[1][dt][j] * inv1[j]);
        }
}

// ---------------- y = attn + dwconv3(v)+b_pe; writes yT (B,N,C) bf16 ----------------
__global__ __launch_bounds__(256) void k_pe_add(const bf16* __restrict__ attnT,
                                                const bf16* __restrict__ vb,
                                                const float* __restrict__ wpe,
                                                const float* __restrict__ bpe,
                                                bf16* __restrict__ yT) {
    __shared__ float vt[64 * 199];  // [c_local][kh*66 + wslot], wslot = w+1, pads at 0 and 65
    int hh = blockIdx.x, c0 = blockIdx.y * 64, b = blockIdx.z;
    int t = threadIdx.x, lane = t & 63, wg = t >> 6;

    if (t < 192) {
        int c_l = t >> 2, kh2 = t & 3;
        if (kh2 < 3) {
            vt[c_l * 199 + kh2 * 66 + 0] = 0.f;
            vt[c_l * 199 + kh2 * 66 + 65] = 0.f;
        }
    }
    if (t >= 192) {
        int u = t - 192;
        int c_l = 48 + (u >> 2), kh2 = u & 3;
        if (kh2 < 3) {
            vt[c_l * 199 + kh2 * 66 + 0] = 0.f;
            vt[c_l * 199 + kh2 * 66 + 65] = 0.f;
        }
    }
#pragma unroll
    for (int kh = 0; kh < 3; ++kh) {
        int hh2 = hh + kh - 1;
        bool ok = (hh2 >= 0 && hh2 < 64);
        for (int ci = 0; ci < 16; ++ci) {
            int c_l = wg * 16 + ci;
            float val = ok ? (float)vb[((size_t)(b * C_ + c0 + c_l)) * N_ + hh2 * 64 + lane] : 0.f;
            vt[c_l * 199 + kh * 66 + 1 + lane] = val;
        }
    }
    __syncthreads();

    int c = c0 + lane;
    float w9[9];
#pragma unroll
    for (int k = 0; k < 9; ++k) w9[k] = wpe[c * 9 + k];
    float bc = bpe[c];
    const float* vrow = vt + lane * 199;

#pragma unroll
    for (int wi = 0; wi < 16; ++wi) {
        int w = wg * 16 + wi;
        float acc = bc;
#pragma unroll
        for (int kh = 0; kh < 3; ++kh)
#pragma unroll
            for (int kw = 0; kw < 3; ++kw)
                acc += vrow[kh * 66 + w + kw] * w9[kh * 3 + kw];
        int n = hh * 64 + w;
        size_t idx = ((size_t)b * N_ + n) * C_ + c;
        yT[idx] = (bf16)((float)attnT[idx] + acc);
    }
}

// ---------------- proj GEMM + residual: x2 = x + Wp @ y + b ----------------
__global__ __launch_bounds__(256) void k_proj(const bf16* __restrict__ wpb,
                                              const bf16* __restrict__ yT,
                                              const float* __restrict__ bias,
                                              const float* __restrict__ x,
                                              float* __restrict__ x2) {
    int n0 = blockIdx.x * 64, o0 = blockIdx.y * 64, b = blockIdx.z;
    int t = threadIdx.x, w = t >> 6, l = t & 63, lr = l & 15, lg = l >> 4;
    const bf16* arow = wpb + (size_t)(o0 + 16 * w + lr) * C_ + 8 * lg;
    const bf16* brow = yT + ((size_t)b * N_ + n0 + lr) * C_ + 8 * lg;
    f32x4 acc[4];
    f32x4 zz = {0.f, 0.f, 0.f, 0.f};
    acc[0] = zz; acc[1] = zz; acc[2] = zz; acc[3] = zz;
    for (int kk = 0; kk < C_; kk += 32) {
        bf16x8 a = *(const bf16x8*)(arow + kk);
#pragma unroll
        for (int tt = 0; tt < 4; ++tt) {
            bf16x8 bb = *(const bf16x8*)(brow + (size_t)tt * 16 * C_ + kk);
            acc[tt] = __builtin_amdgcn_mfma_f32_16x16x32_bf16(a, bb, acc[tt], 0, 0, 0);
        }
    }
#pragma unroll
    for (int tt = 0; tt < 4; ++tt) {
        int n = n0 + 16 * tt + lr;
#pragma unroll
        for (int j = 0; j < 4; ++j) {
            int o = o0 + 16 * w + 4 * lg + j;
            size_t idx = ((size_t)b * C_ + o) * N_ + n;
            x2[idx] = x[idx] + acc[tt][j] + bias[o];
        }
    }
}

// ---------------- channel attention: reduce ----------------
__global__ __launch_bounds__(256) void k_ca_red(const float* __restrict__ x2,
                                                float* __restrict__ avg, float* __restrict__ mx) {
    int bc = blockIdx.x;
    int t = threadIdx.x;
    const float* row = x2 + (size_t)bc * N_;
    float s = 0.f, m = -1e30f;
    for (int i = t; i < N_; i += 256) { float v = row[i]; s += v; m = fmaxf(m, v); }
#pragma unroll
    for (int d = 1; d < 64; d <<= 1) { s += __shfl_xor(s, d); m = fmaxf(m, __shfl_xor(m, d)); }
    __shared__ float ss[4], sm[4];
    int w = t >> 6;
    if ((t & 63) == 0) { ss[w] = s; sm[w] = m; }
    __syncthreads();
    if (t == 0) {
        avg[bc] = (ss[0] + ss[1] + ss[2] + ss[3]) / (float)N_;
        mx[bc] = fmaxf(fmaxf(sm[0], sm[1]), fmaxf(sm[2], sm[3]));
    }
}

// ---------------- channel attention: MLP ----------------
__global__ __launch_bounds__(256) void k_ca_mlp(const float* __restrict__ avg,
                                                const float* __restrict__ mx,
                                                const float* __restrict__ wfc1,
                                                const float* __restrict__ wfc2,
                                                float* __restrict__ ca) {
    int b = blockIdx.x, t = threadIdx.x;
    __shared__ float hsum[16];
    if (t < 16) {
        const float* w1 = wfc1 + t * C_;
        float ha = 0.f, hm = 0.f;
        for (int c = 0; c < C_; ++c) { ha += avg[b * C_ + c] * w1[c]; hm += mx[b * C_ + c] * w1[c]; }
        hsum[t] = fmaxf(ha, 0.f) + fmaxf(hm, 0.f);
    }
    __syncthreads();
    float o = 0.f;
    const float* w2 = wfc2 + t * 16;
#pragma unroll
    for (int r = 0; r < 16; ++r) o += hsum[r] * w2[r];
    ca[b * C_ + t] = 1.f / (1.f + __expf(-o));
}

// ---------------- spatial attention: channel reduce of x2*ca ----------------
__global__ __launch_bounds__(256) void k_sa_red(const float* __restrict__ x2,
                                                const float* __restrict__ ca,
                                                float* __restrict__ sain) {
    int b = blockIdx.y;
    int n = blockIdx.x * 256 + threadIdx.x;
    __shared__ float cal[C_];
    cal[threadIdx.x] = ca[b * C_ + threadIdx.x];
    __syncthreads();
    float s = 0.f, m = -1e30f;
    for (int c = 0; c < C_; ++c) {
        float v = x2[((size_t)b * C_ + c) * N_ + n] * cal[c];
        s += v; m = fmaxf(m, v);
    }
    sain[((size_t)b * 2 + 0) * N_ + n] = s * (1.f / C_);
    sain[((size_t)b * 2 + 1) * N_ + n] = m;
}

// ---------------- final: sa conv + sigmoid + output (f32) ----------------
__global__ __launch_bounds__(256) void k_final(const float* __restrict__ x2,
                                               const float* __restrict__ ca,
                                               const float* __restrict__ sain,
                                               const float* __restrict__ wsa,
                                               float* __restrict__ out) {
    int b = blockIdx.y;
    int n = blockIdx.x * 256 + threadIdx.x;
    __shared__ float cal[C_];
    cal[threadIdx.x] = ca[b * C_ + threadIdx.x];
    __syncthreads();
    int hh = n >> 6, ww = n & 63;
    float acc = 0.f;
#pragma unroll
    for (int i = 0; i < 2; ++i)
#pragma unroll
        for (int kh = 0; kh < 3; ++kh) {
            int hh2 = hh + kh - 1;
            if (hh2 < 0 || hh2 >= 64) continue;
#pragma unroll
            for (int kw = 0; kw < 3; ++kw) {
                int ww2 = ww + kw - 1;
                if (ww2 < 0 || ww2 >= 64) continue;
                acc += sain[((size_t)b * 2 + i) * N_ + hh2 * 64 + ww2] * wsa[i * 9 + kh * 3 + kw];
            }
        }
    float sa = 1.f / (1.f + __expf(-acc));
    for (int c = 0; c < C_; ++c) {
        size_t idx = ((size_t)b * C_ + c) * N_ + n;
        out[idx] = x2[idx] * cal[c] * sa;
    }
}

extern "C" void kernel_launch(void* const* d_in, const int* in_sizes, int n_in,
                              void* d_out, int out_size, void* d_ws, size_t ws_size,
                              hipStream_t stream) {
    const float* x     = (const float*)d_in[0];
    const float* wqkv  = (const float*)d_in[1];
    const float* bqkv  = (const float*)d_in[2];
    const float* wproj = (const float*)d_in[3];
    const float* bproj = (const float*)d_in[4];
    const float* wpe   = (const float*)d_in[5];
    const float* bpe   = (const float*)d_in[6];
    const float* wfc1  = (const float*)d_in[7];
    const float* wfc2  = (const float*)d_in[8];
    const float* wsa   = (const float*)d_in[9];
    float* out = (float*)d_out;

    char* ws = (char*)d_ws;
    size_t off = 0;
    auto alloc = [&](size_t bytes) {
        char* p = ws + off;
        off += (bytes + 255) & ~(size_t)255;
        return p;
    };
    bf16*  qt    = (bf16*)alloc((size_t)B_ * NH_ * N_ * KD_ * 2);
    bf16*  ktb   = (bf16*)alloc((size_t)B_ * NH_ * N_ * KD_ * 2);
    bf16*  vbuf  = (bf16*)alloc((size_t)B_ * NH_ * HD_ * N_ * 2);
    bf16*  xT    = (bf16*)alloc((size_t)B_ * N_ * C_ * 2);
    bf16*  attnT = (bf16*)alloc((size_t)B_ * N_ * C_ * 2);
    float* x2    = (float*)alloc((size_t)B_ * C_ * N_ * 4);
    bf16*  wqb   = (bf16*)alloc((size_t)HQKV_ * C_ * 2);
    bf16*  wpb   = (bf16*)alloc((size_t)C_ * C_ * 2);
    float* avg   = (float*)alloc(B_ * C_ * 4);
    float* mxb   = (float*)alloc(B_ * C_ * 4);
    float* cab   = (float*)alloc(B_ * C_ * 4);
    float* sain  = (float*)alloc((size_t)B_ * 2 * N_ * 4);
    bf16*  yT    = xT;  // alias: xT dead after k_qkv completes (stream-ordered)

    k_convw<<<dim3((HQKV_ * C_ + 255) / 256), 256, 0, stream>>>(wqkv, wproj, wqb, wpb);
    k_transpose<<<dim3(64, 4, B_), 256, 0, stream>>>(x, xT);
    k_qkv<<<dim3(64, 8, B_), 256, 0, stream>>>(wqb, xT, bqkv, qt, ktb, vbuf);
    k_attn<<<dim3(512), 256, 0, stream>>>(qt, ktb, vbuf, attnT);
    k_pe_add<<<dim3(64, 4, B_), 256, 0, stream>>>(attnT, vbuf, wpe, bpe, yT);
    k_proj<<<dim3(64, 4, B_), 256, 0, stream>>>(wpb, yT, bproj, x, x2);
    k_ca_red<<<dim3(B_ * C_), 256, 0, stream>>>(x2, avg, mxb);
    k_ca_mlp<<<dim3(B_), 256, 0, stream>>>(avg, mxb, wfc1, wfc2, cab);
    k_sa_red<<<dim3(16, B_), 256, 0, stream>>>(x2, cab, sain);
    k_final<<<dim3(16, B_), 256, 0, stream>>>(x2, cab, sain, wsa, out);
}